// Round 8
// baseline (718.824 us; speedup 1.0000x reference)
//
#include <hip/hip_runtime.h>
#include <hip/hip_bf16.h>
#include <math.h>

#define DIM 256
#define NHEAD 4
#define HD 64
#define MSPLIT 4

typedef __attribute__((ext_vector_type(8))) short short8b;   // 8 bf16 (4 VGPRs)
typedef __attribute__((ext_vector_type(4))) float f32x4;

union B8 { uint4 u; short8b v; };

__device__ __forceinline__ float sigmoidf_(float x) { return 1.0f / (1.0f + __expf(-x)); }
__device__ __forceinline__ float geluf_(float x) {
    return 0.5f * x * (1.0f + erff(x * 0.70710678118654752440f));
}
__device__ __forceinline__ float wave_sum64(float v) {
    v += __shfl_xor(v, 32); v += __shfl_xor(v, 16); v += __shfl_xor(v, 8);
    v += __shfl_xor(v, 4);  v += __shfl_xor(v, 2);  v += __shfl_xor(v, 1);
    return v;
}
__device__ __forceinline__ unsigned short f2bf(float f) {   // RNE f32->bf16 bits
    union { float f; unsigned int u; } a; a.f = f;
    unsigned int u = a.u;
    unsigned int r = (u + 0x7FFFu + ((u >> 16) & 1u)) >> 16;
    return (unsigned short)r;
}
// single-instruction packed f32x2 -> bf16x2 (no builtin on gfx950; guide T12)
__device__ __forceinline__ unsigned int cvtpk_(float lo, float hi) {
    unsigned int r;
    asm("v_cvt_pk_bf16_f32 %0, %1, %2" : "=v"(r) : "v"(lo), "v"(hi));
    return r;
}

// ---------------------------------------------------------------------------
// fp32 -> bf16 conversion passes (8 elems/thread). GELU variant for agg.
// ---------------------------------------------------------------------------
template<int DO_GELU>
__launch_bounds__(256)
__global__ void cvt_bf16_kernel(const float* __restrict__ src,
                                unsigned short* __restrict__ dst, int n8)
{
    const int i = blockIdx.x * 256 + threadIdx.x;
    if (i >= n8) return;
    float4 a = reinterpret_cast<const float4*>(src)[2 * i];
    float4 b = reinterpret_cast<const float4*>(src)[2 * i + 1];
    if (DO_GELU) {
        a.x = geluf_(a.x); a.y = geluf_(a.y); a.z = geluf_(a.z); a.w = geluf_(a.w);
        b.x = geluf_(b.x); b.y = geluf_(b.y); b.z = geluf_(b.z); b.w = geluf_(b.w);
    }
    ushort4 lo = {f2bf(a.x), f2bf(a.y), f2bf(a.z), f2bf(a.w)};
    ushort4 hi = {f2bf(b.x), f2bf(b.y), f2bf(b.z), f2bf(b.w)};
    reinterpret_cast<ushort4*>(dst)[2 * i] = lo;
    reinterpret_cast<ushort4*>(dst)[2 * i + 1] = hi;
}

// 12 weight chunks of 256x256 fp32 -> bf16 arena. blockIdx.y = chunk.
__launch_bounds__(256)
__global__ void cvt_w_kernel(const float* __restrict__ W0, const float* __restrict__ W1,
                             const float* __restrict__ W2, const float* __restrict__ W3,
                             const float* __restrict__ W4, const float* __restrict__ W5,
                             const float* __restrict__ W6, const float* __restrict__ W7,
                             const float* __restrict__ W8, const float* __restrict__ W9,
                             const float* __restrict__ W10, const float* __restrict__ W11,
                             unsigned short* __restrict__ arena)
{
    const float* s;
    switch (blockIdx.y) {
        case 0: s = W0; break;  case 1: s = W1; break;  case 2: s = W2; break;
        case 3: s = W3; break;  case 4: s = W4; break;  case 5: s = W5; break;
        case 6: s = W6; break;  case 7: s = W7; break;  case 8: s = W8; break;
        case 9: s = W9; break;  case 10: s = W10; break; default: s = W11; break;
    }
    const int i = blockIdx.x * 256 + threadIdx.x;   // 32 blocks x 256 thr x 8 = 65536
    unsigned short* dst = arena + (size_t)blockIdx.y * 65536;
    float4 a = reinterpret_cast<const float4*>(s)[2 * i];
    float4 b = reinterpret_cast<const float4*>(s)[2 * i + 1];
    ushort4 lo = {f2bf(a.x), f2bf(a.y), f2bf(a.z), f2bf(a.w)};
    ushort4 hi = {f2bf(b.x), f2bf(b.y), f2bf(b.z), f2bf(b.w)};
    reinterpret_cast<ushort4*>(dst)[2 * i] = lo;
    reinterpret_cast<ushort4*>(dst)[2 * i + 1] = hi;
}

// ---------------------------------------------------------------------------
// bf16 MFMA GEMM: C[M,Nout] = epilogue( Abf[M,256] @ Wbf^T + bias ).
// Block 256 thr = 4 waves stacked over M (BM=64); wave tile 16x64 (4 N-frags).
// OUT_MODE 0: acc+bias; OUT_MODE 1: sigmoid-skip mix with xres.
// WF32: write fp32 C; WBF: write bf16 mirror Cbf.
// ---------------------------------------------------------------------------
template<int OUT_MODE, int WF32, int WBF>
__launch_bounds__(256)
__global__ void bgemm_kernel(const unsigned short* __restrict__ Abf,
                             const unsigned short* __restrict__ W0b,
                             const unsigned short* __restrict__ W1b,
                             const unsigned short* __restrict__ W2b,
                             const float* __restrict__ B0, const float* __restrict__ B1,
                             const float* __restrict__ B2,
                             float* __restrict__ C, int ldc,
                             unsigned short* __restrict__ Cbf, int ldcb,
                             const float* __restrict__ xres,
                             const float* __restrict__ skipv)
{
    const int t = threadIdx.x;
    const int lane = t & 63;
    const int wid = t >> 6;
    const int col16 = lane & 15;
    const int oct = lane >> 4;
    const int r0 = blockIdx.y * 64 + wid * 16;
    const int c0 = blockIdx.x * 64;
    const int widx = c0 >> 8;
    const unsigned short* W = (widx == 0) ? W0b : (widx == 1 ? W1b : W2b);
    const float* Bv = (widx == 0) ? B0 : (widx == 1 ? B1 : B2);
    const int cw = c0 & 255;

    const unsigned short* aptr = Abf + (size_t)(r0 + col16) * 256 + oct * 8;
    const unsigned short* wptr = W + (size_t)(cw + col16) * 256 + oct * 8;

    f32x4 acc0 = {0,0,0,0}, acc1 = {0,0,0,0}, acc2 = {0,0,0,0}, acc3 = {0,0,0,0};
#pragma unroll
    for (int k0 = 0; k0 < 256; k0 += 32) {
        B8 af, w0, w1, w2, w3;
        af.u = *reinterpret_cast<const uint4*>(aptr + k0);
        w0.u = *reinterpret_cast<const uint4*>(wptr + k0);
        w1.u = *reinterpret_cast<const uint4*>(wptr + k0 + 16 * 256);
        w2.u = *reinterpret_cast<const uint4*>(wptr + k0 + 32 * 256);
        w3.u = *reinterpret_cast<const uint4*>(wptr + k0 + 48 * 256);
        acc0 = __builtin_amdgcn_mfma_f32_16x16x32_bf16(af.v, w0.v, acc0, 0, 0, 0);
        acc1 = __builtin_amdgcn_mfma_f32_16x16x32_bf16(af.v, w1.v, acc1, 0, 0, 0);
        acc2 = __builtin_amdgcn_mfma_f32_16x16x32_bf16(af.v, w2.v, acc2, 0, 0, 0);
        acc3 = __builtin_amdgcn_mfma_f32_16x16x32_bf16(af.v, w3.v, acc3, 0, 0, 0);
    }

    float bias[4];
#pragma unroll
    for (int j = 0; j < 4; ++j) bias[j] = Bv[cw + j * 16 + col16];
    float sg = 0.f;
    if (OUT_MODE == 1) sg = sigmoidf_(skipv[0]);

    const float av[4][4] = {
        {acc0.x, acc0.y, acc0.z, acc0.w}, {acc1.x, acc1.y, acc1.z, acc1.w},
        {acc2.x, acc2.y, acc2.z, acc2.w}, {acc3.x, acc3.y, acc3.z, acc3.w}};
#pragma unroll
    for (int r = 0; r < 4; ++r) {
        const int row = r0 + oct * 4 + r;
#pragma unroll
        for (int j = 0; j < 4; ++j) {
            const int col = c0 + j * 16 + col16;
            float v = av[j][r] + bias[j];
            if (OUT_MODE == 1) {
                const float xv = xres[(size_t)row * ldc + col];
                v = sg * v + (1.f - sg) * xv;
            }
            if (WF32) C[(size_t)row * ldc + col] = v;
            if (WBF)  Cbf[(size_t)row * ldcb + col] = f2bf(v);
        }
    }
}

// ---------------------------------------------------------------------------
// fp32 GEMM (kept for the scoring head only).
// OUT_MODE 2: scores[r] += relu(acc+bias) . w2  (+b2 once)
// ---------------------------------------------------------------------------
template<int IN_GELU, int OUT_MODE>
__launch_bounds__(256)
__global__ void gemm_kernel(const float* __restrict__ A, int lda,
                            const float* __restrict__ W0, const float* __restrict__ W1,
                            const float* __restrict__ W2, int ldw,
                            const float* __restrict__ B0, const float* __restrict__ B1,
                            const float* __restrict__ B2,
                            float* __restrict__ C, int ldc, int Kin,
                            float* __restrict__ scores,
                            const float* __restrict__ w2v,
                            const float* __restrict__ b2v)
{
    __shared__ float As[16][68];
    __shared__ float Ws[16][68];
    const int t = threadIdx.x;
    const int r0 = blockIdx.y * 64;
    const int c0 = blockIdx.x * 64;
    const int widx = c0 >> 8;
    const float* W  = (widx == 0) ? W0 : (widx == 1 ? W1 : W2);
    const float* Bv = (widx == 0) ? B0 : (widx == 1 ? B1 : B2);
    const int cw = c0 & 255;

    const int lrow = t >> 2;
    const int lk   = (t & 3) << 2;
    const int ty = t >> 4, tx = t & 15;

    const float* Aptr = A + (size_t)(r0 + lrow) * lda + lk;
    const float* Wptr = W + (size_t)(cw + lrow) * ldw + lk;

    float acc[4][4] = {};
    for (int k0 = 0; k0 < Kin; k0 += 16) {
        float4 av = *reinterpret_cast<const float4*>(Aptr + k0);
        float4 wv = *reinterpret_cast<const float4*>(Wptr + k0);
        if (IN_GELU) {
            av.x = geluf_(av.x); av.y = geluf_(av.y);
            av.z = geluf_(av.z); av.w = geluf_(av.w);
        }
        As[lk + 0][lrow] = av.x; As[lk + 1][lrow] = av.y;
        As[lk + 2][lrow] = av.z; As[lk + 3][lrow] = av.w;
        Ws[lk + 0][lrow] = wv.x; Ws[lk + 1][lrow] = wv.y;
        Ws[lk + 2][lrow] = wv.z; Ws[lk + 3][lrow] = wv.w;
        __syncthreads();
#pragma unroll
        for (int k = 0; k < 16; ++k) {
            const float4 a = *reinterpret_cast<const float4*>(&As[k][ty << 2]);
            const float4 b = *reinterpret_cast<const float4*>(&Ws[k][tx << 2]);
            const float ar[4] = {a.x, a.y, a.z, a.w};
            const float br[4] = {b.x, b.y, b.z, b.w};
#pragma unroll
            for (int i = 0; i < 4; ++i)
#pragma unroll
                for (int j = 0; j < 4; ++j)
                    acc[i][j] = fmaf(ar[i], br[j], acc[i][j]);
        }
        __syncthreads();
    }

    float bias[4];
#pragma unroll
    for (int j = 0; j < 4; ++j) bias[j] = Bv[cw + (tx << 2) + j];

    if (OUT_MODE == 0) {
#pragma unroll
        for (int i = 0; i < 4; ++i) {
            float4 st;
            st.x = acc[i][0] + bias[0]; st.y = acc[i][1] + bias[1];
            st.z = acc[i][2] + bias[2]; st.w = acc[i][3] + bias[3];
            *reinterpret_cast<float4*>(&C[(size_t)(r0 + (ty << 2) + i) * ldc + c0 + (tx << 2)]) = st;
        }
    } else {
        float wv[4];
#pragma unroll
        for (int j = 0; j < 4; ++j) wv[j] = w2v[c0 + (tx << 2) + j];
#pragma unroll
        for (int i = 0; i < 4; ++i) {
            float p = 0.f;
#pragma unroll
            for (int j = 0; j < 4; ++j)
                p = fmaf(fmaxf(acc[i][j] + bias[j], 0.f), wv[j], p);
            if (c0 == 0 && tx == 0) p += b2v[0];
            atomicAdd(&scores[r0 + (ty << 2) + i], p);
        }
    }
}

// ---------------------------------------------------------------------------
// kt[n, h*64+e] = sum_d kin[n, h*64+d] * arel[h, d, e]      (per-head 64x64)
// ---------------------------------------------------------------------------
__launch_bounds__(256)
__global__ void rel_transform_kernel(const float* __restrict__ kin, int ldin,
                                     const float* __restrict__ arel,
                                     float* __restrict__ kout)
{
    __shared__ float Al[64][68];   // [d][e]
    __shared__ float Kl[64][65];   // [r][d]
    const int t = threadIdx.x;
    const int r0 = blockIdx.x * 64;
    const int h = blockIdx.y;
    const float* ah = arel + h * 4096;
    for (int i = t; i < 1024; i += 256) {
        const int rr = i >> 4, c4 = (i & 15) << 2;
        const float4 av = *reinterpret_cast<const float4*>(&ah[rr * 64 + c4]);
        *reinterpret_cast<float4*>(&Al[rr][c4]) = av;
        const float4 kv = *reinterpret_cast<const float4*>(&kin[(size_t)(r0 + rr) * ldin + h * 64 + c4]);
        Kl[rr][c4 + 0] = kv.x; Kl[rr][c4 + 1] = kv.y;
        Kl[rr][c4 + 2] = kv.z; Kl[rr][c4 + 3] = kv.w;
    }
    __syncthreads();
    const int r  = t & 63;
    const int e0 = (t >> 6) << 4;
    float acc[16] = {};
    for (int d = 0; d < 64; ++d) {
        const float kv = Kl[r][d];
#pragma unroll
        for (int u4 = 0; u4 < 4; ++u4) {
            const float4 a = *reinterpret_cast<const float4*>(&Al[d][e0 + (u4 << 2)]);
            acc[u4 * 4 + 0] = fmaf(kv, a.x, acc[u4 * 4 + 0]);
            acc[u4 * 4 + 1] = fmaf(kv, a.y, acc[u4 * 4 + 1]);
            acc[u4 * 4 + 2] = fmaf(kv, a.z, acc[u4 * 4 + 2]);
            acc[u4 * 4 + 3] = fmaf(kv, a.w, acc[u4 * 4 + 3]);
        }
    }
#pragma unroll
    for (int u4 = 0; u4 < 4; ++u4) {
        float4 st = {acc[u4 * 4 + 0], acc[u4 * 4 + 1], acc[u4 * 4 + 2], acc[u4 * 4 + 3]};
        *reinterpret_cast<float4*>(&kout[(size_t)(r0 + r) * 256 + h * 64 + e0 + (u4 << 2)]) = st;
    }
}

// --------------------------- CSR build -------------------------------------
__global__ void edge_count_kernel(const int* __restrict__ dst, int* __restrict__ cnt, int E)
{
    const int i = blockIdx.x * 256 + threadIdx.x;
    if (i < E) atomicAdd(&cnt[dst[i]], 1);
}

__launch_bounds__(1024)
__global__ void scan_kernel(const int* __restrict__ cnt, int* __restrict__ indptr,
                            int* __restrict__ cursor)
{
    __shared__ int sh[1024];
    const int t = threadIdx.x;
    const int4 v = *reinterpret_cast<const int4*>(&cnt[t << 2]);
    const int sum = v.x + v.y + v.z + v.w;
    sh[t] = sum;
    __syncthreads();
    for (int off = 1; off < 1024; off <<= 1) {
        int x = 0;
        if (t >= off) x = sh[t - off];
        __syncthreads();
        if (t >= off) sh[t] += x;
        __syncthreads();
    }
    int run = sh[t] - sum;
    const int base = t << 2;
    if (t == 0) indptr[0] = 0;
    cursor[base + 0] = run; run += v.x; indptr[base + 1] = run;
    cursor[base + 1] = run; run += v.y; indptr[base + 2] = run;
    cursor[base + 2] = run; run += v.z; indptr[base + 3] = run;
    cursor[base + 3] = run; run += v.w; indptr[base + 4] = run;
}

__global__ void edge_scatter_kernel(const int* __restrict__ src, const int* __restrict__ dst,
                                    int* __restrict__ cursor, int* __restrict__ ssrc, int E)
{
    const int i = blockIdx.x * 256 + threadIdx.x;
    if (i < E) {
        const int p = atomicAdd(&cursor[dst[i]], 1);
        ssrc[p] = src[i];
    }
}

// ---------------------------------------------------------------------------
// HGT edge softmax-aggregate: ONE wave per dst node, all 4 heads at once.
// One-edge-ahead software prefetch of ssrc/K/V hides the gather latency
// under the dot + shfl-reduce + exp of the current edge.
// ---------------------------------------------------------------------------
__launch_bounds__(256)
__global__ void hgt_attn_kernel(const float* __restrict__ qdst,   // q section base, ld=768
                                const float* __restrict__ kt,
                                const float* __restrict__ vt,
                                const float* __restrict__ prel,
                                const int* __restrict__ indptr,
                                const int* __restrict__ ssrc,
                                float* __restrict__ agg)
{
    const int n = blockIdx.x * 4 + (threadIdx.x >> 6);
    const int lane = threadIdx.x & 63;
    const int h = lane >> 4;
    const int d4 = (lane & 15) << 2;
    const float4 q = *reinterpret_cast<const float4*>(&qdst[(size_t)n * 768 + h * 64 + d4]);
    const float ps = prel[h] * 0.125f;
    const int e0 = indptr[n], e1 = indptr[n + 1];
    float m = -1e30f, s = 0.f;
    float4 acc = {0.f, 0.f, 0.f, 0.f};
    float4 kc = {0.f, 0.f, 0.f, 0.f}, vc = {0.f, 0.f, 0.f, 0.f};
    if (e0 < e1) {
        const int sr0 = ssrc[e0];
        kc = *reinterpret_cast<const float4*>(&kt[(size_t)sr0 * 256 + h * 64 + d4]);
        vc = *reinterpret_cast<const float4*>(&vt[(size_t)sr0 * 256 + h * 64 + d4]);
    }
    for (int e = e0; e < e1; ++e) {
        const float4 k = kc, v = vc;
        const int nsr = ssrc[(e + 1 < e1) ? (e + 1) : e];   // clamped prefetch
        kc = *reinterpret_cast<const float4*>(&kt[(size_t)nsr * 256 + h * 64 + d4]);
        vc = *reinterpret_cast<const float4*>(&vt[(size_t)nsr * 256 + h * 64 + d4]);
        float d = q.x * k.x + q.y * k.y + q.z * k.z + q.w * k.w;
        d += __shfl_xor(d, 1); d += __shfl_xor(d, 2);
        d += __shfl_xor(d, 4); d += __shfl_xor(d, 8);
        const float logit = d * ps;
        const float mn = fmaxf(m, logit);
        const float f = __expf(m - mn);
        const float p = __expf(logit - mn);
        s = s * f + p;
        acc.x = acc.x * f + p * v.x;
        acc.y = acc.y * f + p * v.y;
        acc.z = acc.z * f + p * v.z;
        acc.w = acc.w * f + p * v.w;
        m = mn;
    }
    const float inv = 1.f / (s + 1e-16f);
    float4 st = {acc.x * inv, acc.y * inv, acc.z * inv, acc.w * inv};
    *reinterpret_cast<float4*>(&agg[(size_t)n * 256 + h * 64 + d4]) = st;
}

// ---------------------------------------------------------------------------
// V transpose: qkv_bf [N][768] (v section) -> vt[h*64+d][key]  (bf16)
// ---------------------------------------------------------------------------
__launch_bounds__(256)
__global__ void vtrans_kernel(const unsigned short* __restrict__ qkv_bf,
                              unsigned short* __restrict__ vt, int N)
{
    __shared__ unsigned short tile[64][66];
    const int t = threadIdx.x;
    const int k0 = blockIdx.x * 64;
    const int h = blockIdx.y;
    {
        const int key = t >> 2;
        const int d0 = (t & 3) << 4;
        const unsigned short* src = qkv_bf + (size_t)(k0 + key) * 768 + 512 + h * 64 + d0;
        const uint4 a = *reinterpret_cast<const uint4*>(src);
        const uint4 b = *reinterpret_cast<const uint4*>(src + 8);
        const unsigned int w_[8] = {a.x, a.y, a.z, a.w, b.x, b.y, b.z, b.w};
#pragma unroll
        for (int j = 0; j < 8; ++j) {
            tile[d0 + 2 * j][key]     = (unsigned short)(w_[j] & 0xffff);
            tile[d0 + 2 * j + 1][key] = (unsigned short)(w_[j] >> 16);
        }
    }
    __syncthreads();
    {
        const int d = t >> 2;
        const int kk = (t & 3) << 4;
        unsigned int o_[8];
#pragma unroll
        for (int j = 0; j < 8; ++j)
            o_[j] = (unsigned int)tile[d][kk + 2 * j] | ((unsigned int)tile[d][kk + 2 * j + 1] << 16);
        unsigned short* dstp = vt + (size_t)(h * 64 + d) * N + k0 + kk;
        uint4 s0 = {o_[0], o_[1], o_[2], o_[3]};
        uint4 s1 = {o_[4], o_[5], o_[6], o_[7]};
        *reinterpret_cast<uint4*>(dstp) = s0;
        *reinterpret_cast<uint4*>(dstp + 8) = s1;
    }
}

// ---------------------------------------------------------------------------
// MHA via bf16 MFMA, flash-decoding split-K, 2-deep double-buffered K/V
// register prefetch (A/B named sets; static indexing per rule #20).
// ---------------------------------------------------------------------------
__launch_bounds__(256)
__global__ void mha_mfma_kernel(const unsigned short* __restrict__ qkv_bf, // [N][768]
                                const unsigned short* __restrict__ vt_bf,  // [256][N]
                                float* __restrict__ opart,  // [MSPLIT][N][256]
                                float* __restrict__ mpart,  // [MSPLIT][NHEAD][N]
                                float* __restrict__ lpart,  // [MSPLIT][NHEAD][N]
                                int N)
{
    const int lane = threadIdx.x & 63;
    const int g = lane >> 4;
    const int q15 = lane & 15;
    const int gw = blockIdx.x * 4 + (threadIdx.x >> 6);
    const int split = gw & (MSPLIT - 1);
    const int gq = gw >> 2;
    const int h = gq >> 8;
    const int qt = gq & 255;
    const int q0 = qt * 16;
    const int kbeg = split * (N / MSPLIT);
    const int kend = kbeg + (N / MSPLIT);

    B8 qf0, qf1;
    {
        const unsigned short* qp = qkv_bf + (size_t)(q0 + q15) * 768 + h * 64 + g * 8;
        qf0.u = *reinterpret_cast<const uint4*>(qp);
        qf1.u = *reinterpret_cast<const uint4*>(qp + 32);
    }

    f32x4 o0 = {0,0,0,0}, o1 = {0,0,0,0}, o2 = {0,0,0,0}, o3 = {0,0,0,0};
    float m_run = -1e30f, l_run = 0.f;

    const unsigned short* kbase = qkv_bf + 256 + h * 64 + g * 8;
    const unsigned short* vbase = vt_bf + (size_t)(h * 64 + q15) * N + g * 8;
    const int sl0 = (((2 * g) & 3) << 4) + q15;
    const int sl1 = (((2 * g + 1) & 3) << 4) + q15;

    B8 ka0, ka1, ka2, ka3, va0, va1, va2, va3;   // buffer set A
    B8 kb0, kb1, kb2, kb3, vb0, vb1, vb2, vb3;   // buffer set B

    auto loadA = [&](int kk) {
        const unsigned short* kp0 = kbase + (size_t)(kk + q15) * 768;
        const unsigned short* kp1 = kbase + (size_t)(kk + 16 + q15) * 768;
        ka0.u = *reinterpret_cast<const uint4*>(kp0);
        ka1.u = *reinterpret_cast<const uint4*>(kp0 + 32);
        ka2.u = *reinterpret_cast<const uint4*>(kp1);
        ka3.u = *reinterpret_cast<const uint4*>(kp1 + 32);
        const unsigned short* vp = vbase + kk;
        va0.u = *reinterpret_cast<const uint4*>(vp);
        va1.u = *reinterpret_cast<const uint4*>(vp + (size_t)16 * N);
        va2.u = *reinterpret_cast<const uint4*>(vp + (size_t)32 * N);
        va3.u = *reinterpret_cast<const uint4*>(vp + (size_t)48 * N);
    };
    auto loadB = [&](int kk) {
        const unsigned short* kp0 = kbase + (size_t)(kk + q15) * 768;
        const unsigned short* kp1 = kbase + (size_t)(kk + 16 + q15) * 768;
        kb0.u = *reinterpret_cast<const uint4*>(kp0);
        kb1.u = *reinterpret_cast<const uint4*>(kp0 + 32);
        kb2.u = *reinterpret_cast<const uint4*>(kp1);
        kb3.u = *reinterpret_cast<const uint4*>(kp1 + 32);
        const unsigned short* vp = vbase + kk;
        vb0.u = *reinterpret_cast<const uint4*>(vp);
        vb1.u = *reinterpret_cast<const uint4*>(vp + (size_t)16 * N);
        vb2.u = *reinterpret_cast<const uint4*>(vp + (size_t)32 * N);
        vb3.u = *reinterpret_cast<const uint4*>(vp + (size_t)48 * N);
    };
    auto compute = [&](const B8& K0, const B8& K1, const B8& K2, const B8& K3,
                       const B8& V0, const B8& V1, const B8& V2, const B8& V3) {
        f32x4 s0 = {0,0,0,0}, s1 = {0,0,0,0};
        s0 = __builtin_amdgcn_mfma_f32_16x16x32_bf16(K0.v, qf0.v, s0, 0, 0, 0);
        s0 = __builtin_amdgcn_mfma_f32_16x16x32_bf16(K1.v, qf1.v, s0, 0, 0, 0);
        s1 = __builtin_amdgcn_mfma_f32_16x16x32_bf16(K2.v, qf0.v, s1, 0, 0, 0);
        s1 = __builtin_amdgcn_mfma_f32_16x16x32_bf16(K3.v, qf1.v, s1, 0, 0, 0);

        float p[8];
        p[0] = s0.x * 0.125f; p[1] = s0.y * 0.125f; p[2] = s0.z * 0.125f; p[3] = s0.w * 0.125f;
        p[4] = s1.x * 0.125f; p[5] = s1.y * 0.125f; p[6] = s1.z * 0.125f; p[7] = s1.w * 0.125f;

        float mx = fmaxf(fmaxf(fmaxf(p[0], p[1]), fmaxf(p[2], p[3])),
                         fmaxf(fmaxf(p[4], p[5]), fmaxf(p[6], p[7])));
        mx = fmaxf(mx, __shfl_xor(mx, 16));
        mx = fmaxf(mx, __shfl_xor(mx, 32));
        const float mnew = fmaxf(m_run, mx);
        const float f = __expf(m_run - mnew);
        float sum = 0.f;
#pragma unroll
        for (int i = 0; i < 8; ++i) { p[i] = __expf(p[i] - mnew); sum += p[i]; }
        sum += __shfl_xor(sum, 16);
        sum += __shfl_xor(sum, 32);
        l_run = l_run * f + sum;
        m_run = mnew;
        o0 *= f; o1 *= f; o2 *= f; o3 *= f;

        const unsigned int c01a = cvtpk_(p[0], p[1]), c23a = cvtpk_(p[2], p[3]);
        const unsigned int c01b = cvtpk_(p[4], p[5]), c23b = cvtpk_(p[6], p[7]);
        uint4 pu;
        {
            unsigned int x0, x1;
            x0 = (unsigned int)__shfl((int)c01a, sl0); x1 = (unsigned int)__shfl((int)c01b, sl0);
            pu.x = (g < 2) ? x0 : x1;
            x0 = (unsigned int)__shfl((int)c23a, sl0); x1 = (unsigned int)__shfl((int)c23b, sl0);
            pu.y = (g < 2) ? x0 : x1;
            x0 = (unsigned int)__shfl((int)c01a, sl1); x1 = (unsigned int)__shfl((int)c01b, sl1);
            pu.z = (g < 2) ? x0 : x1;
            x0 = (unsigned int)__shfl((int)c23a, sl1); x1 = (unsigned int)__shfl((int)c23b, sl1);
            pu.w = (g < 2) ? x0 : x1;
        }
        B8 pb; pb.u = pu;

        o0 = __builtin_amdgcn_mfma_f32_16x16x32_bf16(V0.v, pb.v, o0, 0, 0, 0);
        o1 = __builtin_amdgcn_mfma_f32_16x16x32_bf16(V1.v, pb.v, o1, 0, 0, 0);
        o2 = __builtin_amdgcn_mfma_f32_16x16x32_bf16(V2.v, pb.v, o2, 0, 0, 0);
        o3 = __builtin_amdgcn_mfma_f32_16x16x32_bf16(V3.v, pb.v, o3, 0, 0, 0);
    };

    loadA(kbeg);
    for (int ck = kbeg; ck < kend; ck += 64) {
        loadB(ck + 32);                                  // prefetch while computing A
        compute(ka0, ka1, ka2, ka3, va0, va1, va2, va3);
        const int nk = (ck + 64 < kend) ? (ck + 64) : kbeg;  // clamped (redundant last iter)
        loadA(nk);                                       // prefetch while computing B
        compute(kb0, kb1, kb2, kb3, vb0, vb1, vb2, vb3);
    }

    float* op = opart + (size_t)split * N * 256 + (size_t)(q0 + q15) * 256 + h * 64 + 4 * g;
#pragma unroll
    for (int r = 0; r < 4; ++r) {
        op[0 * 16 + r] = o0[r];
        op[1 * 16 + r] = o1[r];
        op[2 * 16 + r] = o2[r];
        op[3 * 16 + r] = o3[r];
    }
    if (g == 0) {
        mpart[(size_t)(split * NHEAD + h) * N + q0 + q15] = m_run;
        lpart[(size_t)(split * NHEAD + h) * N + q0 + q15] = l_run;
    }
}

// Combine the MSPLIT partials -> att_o in bf16 (feeds the mha-out bgemm).
__launch_bounds__(256)
__global__ void mha_combine_kernel(const float* __restrict__ opart,
                                   const float* __restrict__ mpart,
                                   const float* __restrict__ lpart,
                                   unsigned short* __restrict__ outpb, int N)
{
    const int q = blockIdx.x;
    const int c = threadIdx.x;
    const int h = c >> 6;
    const size_t base = (size_t)q * 256 + c;
    float m[MSPLIT], l[MSPLIT];
    float M = -1e30f;
#pragma unroll
    for (int s = 0; s < MSPLIT; ++s) {
        m[s] = mpart[(size_t)(s * NHEAD + h) * N + q];
        l[s] = lpart[(size_t)(s * NHEAD + h) * N + q];
        M = fmaxf(M, m[s]);
    }
    float L = 0.f, o = 0.f;
#pragma unroll
    for (int s = 0; s < MSPLIT; ++s) {
        const float w = __expf(m[s] - M);
        L += w * l[s];
        o = fmaf(w, opart[(size_t)s * N * 256 + base], o);
    }
    outpb[base] = f2bf(o / L);
}

// ---------------------------------------------------------------------------
// h_ent = LN(0.9*h_ent + 0.1*h_glob); rel = sigmoid(h_ent . q). Wave per row.
// ---------------------------------------------------------------------------
__launch_bounds__(256)
__global__ void mix_ln_rel_kernel(float* __restrict__ he, const float* __restrict__ hg,
                                  const float* __restrict__ g, const float* __restrict__ b,
                                  const float* __restrict__ q, float* __restrict__ rel)
{
    const int row = (blockIdx.x * 256 + threadIdx.x) >> 6;
    const int lane = threadIdx.x & 63;
    const float4 a = *reinterpret_cast<const float4*>(&he[(size_t)row * 256 + (lane << 2)]);
    const float4 c = *reinterpret_cast<const float4*>(&hg[(size_t)row * 256 + (lane << 2)]);
    float4 v;
    v.x = 0.9f * a.x + 0.1f * c.x; v.y = 0.9f * a.y + 0.1f * c.y;
    v.z = 0.9f * a.z + 0.1f * c.z; v.w = 0.9f * a.w + 0.1f * c.w;
    const float mean = wave_sum64(v.x + v.y + v.z + v.w) * (1.f / 256.f);
    float4 d = {v.x - mean, v.y - mean, v.z - mean, v.w - mean};
    const float var = wave_sum64(d.x * d.x + d.y * d.y + d.z * d.z + d.w * d.w) * (1.f / 256.f);
    const float rs = rsqrtf(var + 1e-5f);
    const float4 gg = *reinterpret_cast<const float4*>(&g[lane << 2]);
    const float4 bb = *reinterpret_cast<const float4*>(&b[lane << 2]);
    float4 y = {d.x * rs * gg.x + bb.x, d.y * rs * gg.y + bb.y,
                d.z * rs * gg.z + bb.z, d.w * rs * gg.w + bb.w};
    *reinterpret_cast<float4*>(&he[(size_t)row * 256 + (lane << 2)]) = y;
    const float4 qq = *reinterpret_cast<const float4*>(&q[lane << 2]);
    const float dq = wave_sum64(y.x * qq.x + y.y * qq.y + y.z * qq.z + y.w * qq.w);
    if (lane == 0) rel[row] = sigmoidf_(dq);
}

// ctx[p] = sum_{e in seg(p)} h_ent[src]*rel[src]. Wave per (p, quarter).
__launch_bounds__(256)
__global__ void ctx_gather_kernel(const float* __restrict__ he, const float* __restrict__ rel,
                                  const int* __restrict__ indptr, const int* __restrict__ ssrc,
                                  float* __restrict__ ctx)
{
    const int gw = (blockIdx.x * 256 + threadIdx.x) >> 6;
    const int lane = threadIdx.x & 63;
    const int p = gw >> 2, qt = gw & 3;
    const int e0 = indptr[p], e1 = indptr[p + 1];
    float acc = 0.f;
    for (int e = e0; e < e1; ++e) {
        const int sr = ssrc[e];
        acc = fmaf(he[(size_t)sr * 256 + qt * 64 + lane], rel[sr], acc);
    }
    ctx[(size_t)p * 256 + qt * 64 + lane] = acc;
}

// h_psg = LN(h_psg + ctx). Wave per row.
__launch_bounds__(256)
__global__ void psg_ln_kernel(float* __restrict__ hp, const float* __restrict__ ctx,
                              const float* __restrict__ g, const float* __restrict__ b)
{
    const int row = (blockIdx.x * 256 + threadIdx.x) >> 6;
    const int lane = threadIdx.x & 63;
    const float4 a = *reinterpret_cast<const float4*>(&hp[(size_t)row * 256 + (lane << 2)]);
    const float4 c = *reinterpret_cast<const float4*>(&ctx[(size_t)row * 256 + (lane << 2)]);
    float4 v = {a.x + c.x, a.y + c.y, a.z + c.z, a.w + c.w};
    const float mean = wave_sum64(v.x + v.y + v.z + v.w) * (1.f / 256.f);
    float4 d = {v.x - mean, v.y - mean, v.z - mean, v.w - mean};
    const float var = wave_sum64(d.x * d.x + d.y * d.y + d.z * d.z + d.w * d.w) * (1.f / 256.f);
    const float rs = rsqrtf(var + 1e-5f);
    const float4 gg = *reinterpret_cast<const float4*>(&g[lane << 2]);
    const float4 bb = *reinterpret_cast<const float4*>(&b[lane << 2]);
    float4 y = {d.x * rs * gg.x + bb.x, d.y * rs * gg.y + bb.y,
                d.z * rs * gg.z + bb.z, d.w * rs * gg.w + bb.w};
    *reinterpret_cast<float4*>(&hp[(size_t)row * 256 + (lane << 2)]) = y;
}

// qterm[j] = b1[j] + w1[j, 256:512] . q
__global__ void qterm_kernel(const float* __restrict__ w1, const float* __restrict__ b1,
                             const float* __restrict__ q, float* __restrict__ qterm)
{
    __shared__ float qs[256];
    const int t = threadIdx.x;
    qs[t] = q[t];
    __syncthreads();
    float s = b1[t];
    for (int k = 0; k < 256; ++k) s = fmaf(w1[(size_t)t * 512 + 256 + k], qs[k], s);
    qterm[t] = s;
}

// ---------------------------------------------------------------------------
extern "C" void kernel_launch(void* const* d_in, const int* in_sizes, int n_in,
                              void* d_out, int out_size, void* d_ws, size_t ws_size,
                              hipStream_t stream)
{
    const float* x_ent = (const float*)d_in[0];
    const float* x_psg = (const float*)d_in[1];
    const float* q_emb = (const float*)d_in[2];
    const float* Wk_e = (const float*)d_in[3];  const float* bk_e = (const float*)d_in[4];
    const float* Wq_e = (const float*)d_in[5];  const float* bq_e = (const float*)d_in[6];
    const float* Wv_e = (const float*)d_in[7];  const float* bv_e = (const float*)d_in[8];
    const float* Wo_e = (const float*)d_in[9];  const float* bo_e = (const float*)d_in[10];
    const float* sk_e = (const float*)d_in[11];
    const float* Wk_p = (const float*)d_in[12]; const float* bk_p = (const float*)d_in[13];
    const float* Wq_p = (const float*)d_in[14]; const float* bq_p = (const float*)d_in[15];
    const float* Wv_p = (const float*)d_in[16]; const float* bv_p = (const float*)d_in[17];
    const float* Wo_p = (const float*)d_in[18]; const float* bo_p = (const float*)d_in[19];
    const float* sk_p = (const float*)d_in[20];
    const float* a_e2p = (const float*)d_in[21];
    const float* m_e2p = (const float*)d_in[22];
    const float* p_e2p = (const float*)d_in[23];
    const float* a_p2e = (const float*)d_in[24];
    const float* m_p2e = (const float*)d_in[25];
    const float* p_p2e = (const float*)d_in[26];
    const float* Wmi = (const float*)d_in[27];  const float* bmi = (const float*)d_in[28];
    const float* Wmo = (const float*)d_in[29];  const float* bmo = (const float*)d_in[30];
    const float* lng_e = (const float*)d_in[31]; const float* lnb_e = (const float*)d_in[32];
    const float* lng_p = (const float*)d_in[33]; const float* lnb_p = (const float*)d_in[34];
    const float* w1 = (const float*)d_in[35];   const float* b1 = (const float*)d_in[36];
    const float* w2 = (const float*)d_in[37];   const float* b2 = (const float*)d_in[38];
    const int* e2p_src = (const int*)d_in[39];
    const int* e2p_dst = (const int*)d_in[40];
    const int* p2e_src = (const int*)d_in[41];
    const int* p2e_dst = (const int*)d_in[42];

    const int NE = in_sizes[0] / DIM;
    const int NP = in_sizes[1] / DIM;
    const int E  = in_sizes[39];
    float* scores = (float*)d_out;

    char* wp = (char*)d_ws;
    auto alloc = [&](size_t bytes) -> void* {
        void* r = (void*)wp;
        wp += (bytes + 255) & ~(size_t)255;
        return r;
    };
    float* kqv_e = (float*)alloc((size_t)NE * 768 * 4);
    float* kqv_p = (float*)alloc((size_t)NP * 768 * 4);
    float* kt_e  = (float*)alloc((size_t)NE * 256 * 4);
    float* vt_e  = (float*)alloc((size_t)NE * 256 * 4);
    float* kt_p  = (float*)alloc((size_t)NP * 256 * 4);
    float* vt_p  = (float*)alloc((size_t)NP * 256 * 4);
    float* agg_p = (float*)alloc((size_t)NP * 256 * 4);
    float* agg_e = (float*)alloc((size_t)NE * 256 * 4);
    float* h_ent = (float*)alloc((size_t)NE * 256 * 4);
    float* h_psg = (float*)alloc((size_t)NP * 256 * 4);
    float* h_glob= (float*)alloc((size_t)NE * 256 * 4);
    float* relv  = (float*)alloc((size_t)NE * 4);
    float* ctxb  = (float*)alloc((size_t)NP * 256 * 4);
    float* qterm = (float*)alloc(256 * 4);
    unsigned short* warena  = (unsigned short*)alloc((size_t)12 * 65536 * 2);
    unsigned short* xe_bf   = (unsigned short*)alloc((size_t)NE * 256 * 2);
    unsigned short* xp_bf   = (unsigned short*)alloc((size_t)NP * 256 * 2);
    unsigned short* ge_bf   = (unsigned short*)alloc((size_t)NE * 256 * 2);
    unsigned short* gp_bf   = (unsigned short*)alloc((size_t)NP * 256 * 2);
    unsigned short* hent_bf = (unsigned short*)alloc((size_t)NE * 256 * 2);
    unsigned short* atto_bf = (unsigned short*)alloc((size_t)NE * 256 * 2);
    unsigned short* qkv_bf  = (unsigned short*)alloc((size_t)NE * 768 * 2);
    unsigned short* vt_bf   = (unsigned short*)alloc((size_t)256 * NE * 2);
    float* mpart = (float*)alloc((size_t)MSPLIT * NHEAD * NE * 4);
    float* lpart = (float*)alloc((size_t)MSPLIT * NHEAD * NE * 4);
    // opart (MSPLIT*NE*256 fp32 = 16 MB) aliases kqv_e+kqv_p (24 MB contiguous):
    // both dead once the hgt_attn dispatches complete, before mha_mfma runs.
    float* opart = kqv_e;
    int* cnt_a = (int*)alloc((size_t)NP * 4);
    int* cur_a = (int*)alloc((size_t)NP * 4);
    int* ip_a  = (int*)alloc((size_t)(NP + 1) * 4);
    int* ss_a  = (int*)alloc((size_t)E * 4);
    int* cnt_b = (int*)alloc((size_t)NE * 4);
    int* cur_b = (int*)alloc((size_t)NE * 4);
    int* ip_b  = (int*)alloc((size_t)(NE + 1) * 4);
    int* ss_b  = (int*)alloc((size_t)E * 4);

    hipMemsetAsync(cnt_a, 0, (size_t)NP * 4, stream);
    hipMemsetAsync(cnt_b, 0, (size_t)NE * 4, stream);
    hipMemsetAsync(d_out, 0, (size_t)out_size * 4, stream);

    // ---- bf16 conversions (weights + inputs) ----
    cvt_w_kernel<<<dim3(32, 12), 256, 0, stream>>>(
        Wk_e, Wq_e, Wv_e, Wo_e, Wk_p, Wq_p, Wv_p, Wo_p,
        Wmi, Wmi + 65536, Wmi + 131072, Wmo, warena);
    cvt_bf16_kernel<0><<<NE * 256 / 2048, 256, 0, stream>>>(x_ent, xe_bf, NE * 32);
    cvt_bf16_kernel<0><<<NP * 256 / 2048, 256, 0, stream>>>(x_psg, xp_bf, NP * 32);

    const int eb = (E + 255) / 256;
    edge_count_kernel<<<eb, 256, 0, stream>>>(e2p_dst, cnt_a, E);
    edge_count_kernel<<<eb, 256, 0, stream>>>(p2e_dst, cnt_b, E);
    scan_kernel<<<1, 1024, 0, stream>>>(cnt_a, ip_a, cur_a);
    scan_kernel<<<1, 1024, 0, stream>>>(cnt_b, ip_b, cur_b);
    edge_scatter_kernel<<<eb, 256, 0, stream>>>(e2p_src, e2p_dst, cur_a, ss_a, E);
    edge_scatter_kernel<<<eb, 256, 0, stream>>>(p2e_src, p2e_dst, cur_b, ss_b, E);

    // HGT k|q|v projections (bf16 MFMA)
    bgemm_kernel<0,1,0><<<dim3(12, NE / 64), 256, 0, stream>>>(
        xe_bf, warena, warena + 65536, warena + 131072, bk_e, bq_e, bv_e,
        kqv_e, 768, nullptr, 0, nullptr, nullptr);
    bgemm_kernel<0,1,0><<<dim3(12, NP / 64), 256, 0, stream>>>(
        xp_bf, warena + 4*65536, warena + 5*65536, warena + 6*65536, bk_p, bq_p, bv_p,
        kqv_p, 768, nullptr, 0, nullptr, nullptr);

    rel_transform_kernel<<<dim3(NE / 64, NHEAD), 256, 0, stream>>>(kqv_e + 0,   768, a_e2p, kt_e);
    rel_transform_kernel<<<dim3(NE / 64, NHEAD), 256, 0, stream>>>(kqv_e + 512, 768, m_e2p, vt_e);
    rel_transform_kernel<<<dim3(NP / 64, NHEAD), 256, 0, stream>>>(kqv_p + 0,   768, a_p2e, kt_p);
    rel_transform_kernel<<<dim3(NP / 64, NHEAD), 256, 0, stream>>>(kqv_p + 512, 768, m_p2e, vt_p);

    hgt_attn_kernel<<<NP / 4, 256, 0, stream>>>(kqv_p + 256, kt_e, vt_e, p_e2p, ip_a, ss_a, agg_p);
    hgt_attn_kernel<<<NE / 4, 256, 0, stream>>>(kqv_e + 256, kt_p, vt_p, p_p2e, ip_b, ss_b, agg_e);

    // HGT out: gelu+cvt, then bf16 MFMA GEMM with sigmoid-skip epilogue
    cvt_bf16_kernel<1><<<NE * 256 / 2048, 256, 0, stream>>>(agg_e, ge_bf, NE * 32);
    cvt_bf16_kernel<1><<<NP * 256 / 2048, 256, 0, stream>>>(agg_p, gp_bf, NP * 32);
    bgemm_kernel<1,1,1><<<dim3(4, NE / 64), 256, 0, stream>>>(
        ge_bf, warena + 3*65536, warena + 3*65536, warena + 3*65536, bo_e, bo_e, bo_e,
        h_ent, 256, hent_bf, 256, x_ent, sk_e);
    bgemm_kernel<1,1,0><<<dim3(4, NP / 64), 256, 0, stream>>>(
        gp_bf, warena + 7*65536, warena + 7*65536, warena + 7*65536, bo_p, bo_p, bo_p,
        h_psg, 256, nullptr, 0, x_psg, sk_p);

    // MHA: qkv projection (bf16-only out), V-transpose, split-K MFMA flash,
    // combine (bf16 out), out projection
    bgemm_kernel<0,0,1><<<dim3(12, NE / 64), 256, 0, stream>>>(
        hent_bf, warena + 8*65536, warena + 9*65536, warena + 10*65536,
        bmi, bmi + 256, bmi + 512,
        nullptr, 0, qkv_bf, 768, nullptr, nullptr);
    vtrans_kernel<<<dim3(NE / 64, NHEAD), 256, 0, stream>>>(qkv_bf, vt_bf, NE);
    mha_mfma_kernel<<<NHEAD * (NE / 16) * MSPLIT / 4, 256, 0, stream>>>(
        qkv_bf, vt_bf, opart, mpart, lpart, NE);
    mha_combine_kernel<<<NE, 256, 0, stream>>>(opart, mpart, lpart, atto_bf, NE);
    bgemm_kernel<0,1,0><<<dim3(4, NE / 64), 256, 0, stream>>>(
        atto_bf, warena + 11*65536, warena + 11*65536, warena + 11*65536, bmo, bmo, bmo,
        h_glob, 256, nullptr, 0, nullptr, nullptr);

    mix_ln_rel_kernel<<<NE / 4, 256, 0, stream>>>(h_ent, h_glob, lng_e, lnb_e, q_emb, relv);

    ctx_gather_kernel<<<NP, 256, 0, stream>>>(h_ent, relv, ip_a, ss_a, ctxb);
    psg_ln_kernel<<<NP / 4, 256, 0, stream>>>(h_psg, ctxb, lng_p, lnb_p);

    // scoring head (kept fp32)
    qterm_kernel<<<1, 256, 0, stream>>>(w1, b1, q_emb, qterm);
    gemm_kernel<0,2><<<dim3(4, NP / 64), 256, 0, stream>>>(
        h_psg, 256, w1, w1, w1, 512, qterm, qterm, qterm,
        nullptr, 256, 256, scores, w2, b2);
}

// Round 10
// 673.741 us; speedup vs baseline: 1.0669x; 1.0669x over previous
//
#include <hip/hip_runtime.h>
#include <hip/hip_bf16.h>
#include <math.h>

#define DIM 256
#define NHEAD 4
#define HD 64
#define MSPLIT 8

typedef __attribute__((ext_vector_type(8))) short short8b;   // 8 bf16 (4 VGPRs)
typedef __attribute__((ext_vector_type(4))) float f32x4;
typedef __attribute__((ext_vector_type(16))) float f32x16;
typedef __attribute__((ext_vector_type(2))) unsigned int uint2v;

union B8 { uint4 u; short8b v; };

__device__ __forceinline__ float sigmoidf_(float x) { return 1.0f / (1.0f + __expf(-x)); }
__device__ __forceinline__ float geluf_(float x) {
    return 0.5f * x * (1.0f + erff(x * 0.70710678118654752440f));
}
__device__ __forceinline__ float wave_sum64(float v) {
    v += __shfl_xor(v, 32); v += __shfl_xor(v, 16); v += __shfl_xor(v, 8);
    v += __shfl_xor(v, 4);  v += __shfl_xor(v, 2);  v += __shfl_xor(v, 1);
    return v;
}
__device__ __forceinline__ unsigned short f2bf(float f) {   // RNE f32->bf16 bits
    union { float f; unsigned int u; } a; a.f = f;
    unsigned int u = a.u;
    unsigned int r = (u + 0x7FFFu + ((u >> 16) & 1u)) >> 16;
    return (unsigned short)r;
}
// single-instruction packed f32x2 -> bf16x2 (no builtin on gfx950; guide T12)
__device__ __forceinline__ unsigned int cvtpk_(float lo, float hi) {
    unsigned int r;
    asm("v_cvt_pk_bf16_f32 %0, %1, %2" : "=v"(r) : "v"(lo), "v"(hi));
    return r;
}
// permlane32_swap: r[0] = {a.lanes0-31, b.lanes0-31}, r[1] = {a.lanes32-63, b.lanes32-63}
__device__ __forceinline__ uint2v plswap_(unsigned int a, unsigned int b) {
    return __builtin_amdgcn_permlane32_swap(a, b, false, false);
}

// ---------------------------------------------------------------------------
// fp32 -> bf16 conversion passes (8 elems/thread). GELU variant for agg.
// ---------------------------------------------------------------------------
template<int DO_GELU>
__launch_bounds__(256)
__global__ void cvt_bf16_kernel(const float* __restrict__ src,
                                unsigned short* __restrict__ dst, int n8)
{
    const int i = blockIdx.x * 256 + threadIdx.x;
    if (i >= n8) return;
    float4 a = reinterpret_cast<const float4*>(src)[2 * i];
    float4 b = reinterpret_cast<const float4*>(src)[2 * i + 1];
    if (DO_GELU) {
        a.x = geluf_(a.x); a.y = geluf_(a.y); a.z = geluf_(a.z); a.w = geluf_(a.w);
        b.x = geluf_(b.x); b.y = geluf_(b.y); b.z = geluf_(b.z); b.w = geluf_(b.w);
    }
    ushort4 lo = {f2bf(a.x), f2bf(a.y), f2bf(a.z), f2bf(a.w)};
    ushort4 hi = {f2bf(b.x), f2bf(b.y), f2bf(b.z), f2bf(b.w)};
    reinterpret_cast<ushort4*>(dst)[2 * i] = lo;
    reinterpret_cast<ushort4*>(dst)[2 * i + 1] = hi;
}

// 12 weight chunks of 256x256 fp32 -> bf16 arena. blockIdx.y = chunk.
__launch_bounds__(256)
__global__ void cvt_w_kernel(const float* __restrict__ W0, const float* __restrict__ W1,
                             const float* __restrict__ W2, const float* __restrict__ W3,
                             const float* __restrict__ W4, const float* __restrict__ W5,
                             const float* __restrict__ W6, const float* __restrict__ W7,
                             const float* __restrict__ W8, const float* __restrict__ W9,
                             const float* __restrict__ W10, const float* __restrict__ W11,
                             unsigned short* __restrict__ arena)
{
    const float* s;
    switch (blockIdx.y) {
        case 0: s = W0; break;  case 1: s = W1; break;  case 2: s = W2; break;
        case 3: s = W3; break;  case 4: s = W4; break;  case 5: s = W5; break;
        case 6: s = W6; break;  case 7: s = W7; break;  case 8: s = W8; break;
        case 9: s = W9; break;  case 10: s = W10; break; default: s = W11; break;
    }
    const int i = blockIdx.x * 256 + threadIdx.x;   // 32 blocks x 256 thr x 8 = 65536
    unsigned short* dst = arena + (size_t)blockIdx.y * 65536;
    float4 a = reinterpret_cast<const float4*>(s)[2 * i];
    float4 b = reinterpret_cast<const float4*>(s)[2 * i + 1];
    ushort4 lo = {f2bf(a.x), f2bf(a.y), f2bf(a.z), f2bf(a.w)};
    ushort4 hi = {f2bf(b.x), f2bf(b.y), f2bf(b.z), f2bf(b.w)};
    reinterpret_cast<ushort4*>(dst)[2 * i] = lo;
    reinterpret_cast<ushort4*>(dst)[2 * i + 1] = hi;
}

// ---------------------------------------------------------------------------
// bf16 MFMA GEMM: C[M,Nout] = epilogue( Abf[M,256] @ Wbf^T + bias ).
// ---------------------------------------------------------------------------
template<int OUT_MODE, int WF32, int WBF>
__launch_bounds__(256)
__global__ void bgemm_kernel(const unsigned short* __restrict__ Abf,
                             const unsigned short* __restrict__ W0b,
                             const unsigned short* __restrict__ W1b,
                             const unsigned short* __restrict__ W2b,
                             const float* __restrict__ B0, const float* __restrict__ B1,
                             const float* __restrict__ B2,
                             float* __restrict__ C, int ldc,
                             unsigned short* __restrict__ Cbf, int ldcb,
                             const float* __restrict__ xres,
                             const float* __restrict__ skipv)
{
    const int t = threadIdx.x;
    const int lane = t & 63;
    const int wid = t >> 6;
    const int col16 = lane & 15;
    const int oct = lane >> 4;
    const int r0 = blockIdx.y * 64 + wid * 16;
    const int c0 = blockIdx.x * 64;
    const int widx = c0 >> 8;
    const unsigned short* W = (widx == 0) ? W0b : (widx == 1 ? W1b : W2b);
    const float* Bv = (widx == 0) ? B0 : (widx == 1 ? B1 : B2);
    const int cw = c0 & 255;

    const unsigned short* aptr = Abf + (size_t)(r0 + col16) * 256 + oct * 8;
    const unsigned short* wptr = W + (size_t)(cw + col16) * 256 + oct * 8;

    f32x4 acc0 = {0,0,0,0}, acc1 = {0,0,0,0}, acc2 = {0,0,0,0}, acc3 = {0,0,0,0};
#pragma unroll
    for (int k0 = 0; k0 < 256; k0 += 32) {
        B8 af, w0, w1, w2, w3;
        af.u = *reinterpret_cast<const uint4*>(aptr + k0);
        w0.u = *reinterpret_cast<const uint4*>(wptr + k0);
        w1.u = *reinterpret_cast<const uint4*>(wptr + k0 + 16 * 256);
        w2.u = *reinterpret_cast<const uint4*>(wptr + k0 + 32 * 256);
        w3.u = *reinterpret_cast<const uint4*>(wptr + k0 + 48 * 256);
        acc0 = __builtin_amdgcn_mfma_f32_16x16x32_bf16(af.v, w0.v, acc0, 0, 0, 0);
        acc1 = __builtin_amdgcn_mfma_f32_16x16x32_bf16(af.v, w1.v, acc1, 0, 0, 0);
        acc2 = __builtin_amdgcn_mfma_f32_16x16x32_bf16(af.v, w2.v, acc2, 0, 0, 0);
        acc3 = __builtin_amdgcn_mfma_f32_16x16x32_bf16(af.v, w3.v, acc3, 0, 0, 0);
    }

    float bias[4];
#pragma unroll
    for (int j = 0; j < 4; ++j) bias[j] = Bv[cw + j * 16 + col16];
    float sg = 0.f;
    if (OUT_MODE == 1) sg = sigmoidf_(skipv[0]);

    const float av[4][4] = {
        {acc0.x, acc0.y, acc0.z, acc0.w}, {acc1.x, acc1.y, acc1.z, acc1.w},
        {acc2.x, acc2.y, acc2.z, acc2.w}, {acc3.x, acc3.y, acc3.z, acc3.w}};
#pragma unroll
    for (int r = 0; r < 4; ++r) {
        const int row = r0 + oct * 4 + r;
#pragma unroll
        for (int j = 0; j < 4; ++j) {
            const int col = c0 + j * 16 + col16;
            float v = av[j][r] + bias[j];
            if (OUT_MODE == 1) {
                const float xv = xres[(size_t)row * ldc + col];
                v = sg * v + (1.f - sg) * xv;
            }
            if (WF32) C[(size_t)row * ldc + col] = v;
            if (WBF)  Cbf[(size_t)row * ldcb + col] = f2bf(v);
        }
    }
}

// ---------------------------------------------------------------------------
// fp32 GEMM (kept for the scoring head only).
// ---------------------------------------------------------------------------
template<int IN_GELU, int OUT_MODE>
__launch_bounds__(256)
__global__ void gemm_kernel(const float* __restrict__ A, int lda,
                            const float* __restrict__ W0, const float* __restrict__ W1,
                            const float* __restrict__ W2, int ldw,
                            const float* __restrict__ B0, const float* __restrict__ B1,
                            const float* __restrict__ B2,
                            float* __restrict__ C, int ldc, int Kin,
                            float* __restrict__ scores,
                            const float* __restrict__ w2v,
                            const float* __restrict__ b2v)
{
    __shared__ float As[16][68];
    __shared__ float Ws[16][68];
    const int t = threadIdx.x;
    const int r0 = blockIdx.y * 64;
    const int c0 = blockIdx.x * 64;
    const int widx = c0 >> 8;
    const float* W  = (widx == 0) ? W0 : (widx == 1 ? W1 : W2);
    const float* Bv = (widx == 0) ? B0 : (widx == 1 ? B1 : B2);
    const int cw = c0 & 255;

    const int lrow = t >> 2;
    const int lk   = (t & 3) << 2;
    const int ty = t >> 4, tx = t & 15;

    const float* Aptr = A + (size_t)(r0 + lrow) * lda + lk;
    const float* Wptr = W + (size_t)(cw + lrow) * ldw + lk;

    float acc[4][4] = {};
    for (int k0 = 0; k0 < Kin; k0 += 16) {
        float4 av = *reinterpret_cast<const float4*>(Aptr + k0);
        float4 wv = *reinterpret_cast<const float4*>(Wptr + k0);
        if (IN_GELU) {
            av.x = geluf_(av.x); av.y = geluf_(av.y);
            av.z = geluf_(av.z); av.w = geluf_(av.w);
        }
        As[lk + 0][lrow] = av.x; As[lk + 1][lrow] = av.y;
        As[lk + 2][lrow] = av.z; As[lk + 3][lrow] = av.w;
        Ws[lk + 0][lrow] = wv.x; Ws[lk + 1][lrow] = wv.y;
        Ws[lk + 2][lrow] = wv.z; Ws[lk + 3][lrow] = wv.w;
        __syncthreads();
#pragma unroll
        for (int k = 0; k < 16; ++k) {
            const float4 a = *reinterpret_cast<const float4*>(&As[k][ty << 2]);
            const float4 b = *reinterpret_cast<const float4*>(&Ws[k][tx << 2]);
            const float ar[4] = {a.x, a.y, a.z, a.w};
            const float br[4] = {b.x, b.y, b.z, b.w};
#pragma unroll
            for (int i = 0; i < 4; ++i)
#pragma unroll
                for (int j = 0; j < 4; ++j)
                    acc[i][j] = fmaf(ar[i], br[j], acc[i][j]);
        }
        __syncthreads();
    }

    float bias[4];
#pragma unroll
    for (int j = 0; j < 4; ++j) bias[j] = Bv[cw + (tx << 2) + j];

    if (OUT_MODE == 0) {
#pragma unroll
        for (int i = 0; i < 4; ++i) {
            float4 st;
            st.x = acc[i][0] + bias[0]; st.y = acc[i][1] + bias[1];
            st.z = acc[i][2] + bias[2]; st.w = acc[i][3] + bias[3];
            *reinterpret_cast<float4*>(&C[(size_t)(r0 + (ty << 2) + i) * ldc + c0 + (tx << 2)]) = st;
        }
    } else {
        float wv[4];
#pragma unroll
        for (int j = 0; j < 4; ++j) wv[j] = w2v[c0 + (tx << 2) + j];
#pragma unroll
        for (int i = 0; i < 4; ++i) {
            float p = 0.f;
#pragma unroll
            for (int j = 0; j < 4; ++j)
                p = fmaf(fmaxf(acc[i][j] + bias[j], 0.f), wv[j], p);
            if (c0 == 0 && tx == 0) p += b2v[0];
            atomicAdd(&scores[r0 + (ty << 2) + i], p);
        }
    }
}

// ---------------------------------------------------------------------------
// kt[n, h*64+e] = sum_d kin[n, h*64+d] * arel[h, d, e]      (per-head 64x64)
// ---------------------------------------------------------------------------
__launch_bounds__(256)
__global__ void rel_transform_kernel(const float* __restrict__ kin, int ldin,
                                     const float* __restrict__ arel,
                                     float* __restrict__ kout)
{
    __shared__ float Al[64][68];   // [d][e]
    __shared__ float Kl[64][65];   // [r][d]
    const int t = threadIdx.x;
    const int r0 = blockIdx.x * 64;
    const int h = blockIdx.y;
    const float* ah = arel + h * 4096;
    for (int i = t; i < 1024; i += 256) {
        const int rr = i >> 4, c4 = (i & 15) << 2;
        const float4 av = *reinterpret_cast<const float4*>(&ah[rr * 64 + c4]);
        *reinterpret_cast<float4*>(&Al[rr][c4]) = av;
        const float4 kv = *reinterpret_cast<const float4*>(&kin[(size_t)(r0 + rr) * ldin + h * 64 + c4]);
        Kl[rr][c4 + 0] = kv.x; Kl[rr][c4 + 1] = kv.y;
        Kl[rr][c4 + 2] = kv.z; Kl[rr][c4 + 3] = kv.w;
    }
    __syncthreads();
    const int r  = t & 63;
    const int e0 = (t >> 6) << 4;
    float acc[16] = {};
    for (int d = 0; d < 64; ++d) {
        const float kv = Kl[r][d];
#pragma unroll
        for (int u4 = 0; u4 < 4; ++u4) {
            const float4 a = *reinterpret_cast<const float4*>(&Al[d][e0 + (u4 << 2)]);
            acc[u4 * 4 + 0] = fmaf(kv, a.x, acc[u4 * 4 + 0]);
            acc[u4 * 4 + 1] = fmaf(kv, a.y, acc[u4 * 4 + 1]);
            acc[u4 * 4 + 2] = fmaf(kv, a.z, acc[u4 * 4 + 2]);
            acc[u4 * 4 + 3] = fmaf(kv, a.w, acc[u4 * 4 + 3]);
        }
    }
#pragma unroll
    for (int u4 = 0; u4 < 4; ++u4) {
        float4 st = {acc[u4 * 4 + 0], acc[u4 * 4 + 1], acc[u4 * 4 + 2], acc[u4 * 4 + 3]};
        *reinterpret_cast<float4*>(&kout[(size_t)(r0 + r) * 256 + h * 64 + e0 + (u4 << 2)]) = st;
    }
}

// --------------------------- CSR build -------------------------------------
__global__ void edge_count_kernel(const int* __restrict__ dst, int* __restrict__ cnt, int E)
{
    const int i = blockIdx.x * 256 + threadIdx.x;
    if (i < E) atomicAdd(&cnt[dst[i]], 1);
}

__launch_bounds__(1024)
__global__ void scan_kernel(const int* __restrict__ cnt, int* __restrict__ indptr,
                            int* __restrict__ cursor)
{
    __shared__ int sh[1024];
    const int t = threadIdx.x;
    const int4 v = *reinterpret_cast<const int4*>(&cnt[t << 2]);
    const int sum = v.x + v.y + v.z + v.w;
    sh[t] = sum;
    __syncthreads();
    for (int off = 1; off < 1024; off <<= 1) {
        int x = 0;
        if (t >= off) x = sh[t - off];
        __syncthreads();
        if (t >= off) sh[t] += x;
        __syncthreads();
    }
    int run = sh[t] - sum;
    const int base = t << 2;
    if (t == 0) indptr[0] = 0;
    cursor[base + 0] = run; run += v.x; indptr[base + 1] = run;
    cursor[base + 1] = run; run += v.y; indptr[base + 2] = run;
    cursor[base + 2] = run; run += v.z; indptr[base + 3] = run;
    cursor[base + 3] = run; run += v.w; indptr[base + 4] = run;
}

__global__ void edge_scatter_kernel(const int* __restrict__ src, const int* __restrict__ dst,
                                    int* __restrict__ cursor, int* __restrict__ ssrc, int E)
{
    const int i = blockIdx.x * 256 + threadIdx.x;
    if (i < E) {
        const int p = atomicAdd(&cursor[dst[i]], 1);
        ssrc[p] = src[i];
    }
}

// ---------------------------------------------------------------------------
// HGT edge softmax-aggregate: ONE wave per dst node, all 4 heads at once,
// one-edge-ahead software prefetch (round-8 verified baseline).
// ---------------------------------------------------------------------------
__launch_bounds__(256)
__global__ void hgt_attn_kernel(const float* __restrict__ qdst,   // q section base, ld=768
                                const float* __restrict__ kt,
                                const float* __restrict__ vt,
                                const float* __restrict__ prel,
                                const int* __restrict__ indptr,
                                const int* __restrict__ ssrc,
                                float* __restrict__ agg)
{
    const int n = blockIdx.x * 4 + (threadIdx.x >> 6);
    const int lane = threadIdx.x & 63;
    const int h = lane >> 4;
    const int d4 = (lane & 15) << 2;
    const float4 q = *reinterpret_cast<const float4*>(&qdst[(size_t)n * 768 + h * 64 + d4]);
    const float ps = prel[h] * 0.125f;
    const int e0 = indptr[n], e1 = indptr[n + 1];
    float m = -1e30f, s = 0.f;
    float4 acc = {0.f, 0.f, 0.f, 0.f};
    float4 kc = {0.f, 0.f, 0.f, 0.f}, vc = {0.f, 0.f, 0.f, 0.f};
    if (e0 < e1) {
        const int sr0 = ssrc[e0];
        kc = *reinterpret_cast<const float4*>(&kt[(size_t)sr0 * 256 + h * 64 + d4]);
        vc = *reinterpret_cast<const float4*>(&vt[(size_t)sr0 * 256 + h * 64 + d4]);
    }
    for (int e = e0; e < e1; ++e) {
        const float4 k = kc, v = vc;
        const int nsr = ssrc[(e + 1 < e1) ? (e + 1) : e];   // clamped prefetch
        kc = *reinterpret_cast<const float4*>(&kt[(size_t)nsr * 256 + h * 64 + d4]);
        vc = *reinterpret_cast<const float4*>(&vt[(size_t)nsr * 256 + h * 64 + d4]);
        float d = q.x * k.x + q.y * k.y + q.z * k.z + q.w * k.w;
        d += __shfl_xor(d, 1); d += __shfl_xor(d, 2);
        d += __shfl_xor(d, 4); d += __shfl_xor(d, 8);
        const float logit = d * ps;
        const float mn = fmaxf(m, logit);
        const float f = __expf(m - mn);
        const float p = __expf(logit - mn);
        s = s * f + p;
        acc.x = acc.x * f + p * v.x;
        acc.y = acc.y * f + p * v.y;
        acc.z = acc.z * f + p * v.z;
        acc.w = acc.w * f + p * v.w;
        m = mn;
    }
    const float inv = 1.f / (s + 1e-16f);
    float4 st = {acc.x * inv, acc.y * inv, acc.z * inv, acc.w * inv};
    *reinterpret_cast<float4*>(&agg[(size_t)n * 256 + h * 64 + d4]) = st;
}

// ---------------------------------------------------------------------------
// V transpose: qkv_bf [N][768] (v section) -> vt[h*64+d][key]  (bf16)
// ---------------------------------------------------------------------------
__launch_bounds__(256)
__global__ void vtrans_kernel(const unsigned short* __restrict__ qkv_bf,
                              unsigned short* __restrict__ vt, int N)
{
    __shared__ unsigned short tile[64][66];
    const int t = threadIdx.x;
    const int k0 = blockIdx.x * 64;
    const int h = blockIdx.y;
    {
        const int key = t >> 2;
        const int d0 = (t & 3) << 4;
        const unsigned short* src = qkv_bf + (size_t)(k0 + key) * 768 + 512 + h * 64 + d0;
        const uint4 a = *reinterpret_cast<const uint4*>(src);
        const uint4 b = *reinterpret_cast<const uint4*>(src + 8);
        const unsigned int w_[8] = {a.x, a.y, a.z, a.w, b.x, b.y, b.z, b.w};
#pragma unroll
        for (int j = 0; j < 8; ++j) {
            tile[d0 + 2 * j][key]     = (unsigned short)(w_[j] & 0xffff);
            tile[d0 + 2 * j + 1][key] = (unsigned short)(w_[j] >> 16);
        }
    }
    __syncthreads();
    {
        const int d = t >> 2;
        const int kk = (t & 3) << 4;
        unsigned int o_[8];
#pragma unroll
        for (int j = 0; j < 8; ++j)
            o_[j] = (unsigned int)tile[d][kk + 2 * j] | ((unsigned int)tile[d][kk + 2 * j + 1] << 16);
        unsigned short* dstp = vt + (size_t)(h * 64 + d) * N + k0 + kk;
        uint4 s0 = {o_[0], o_[1], o_[2], o_[3]};
        uint4 s1 = {o_[4], o_[5], o_[6], o_[7]};
        *reinterpret_cast<uint4*>(dstp) = s0;
        *reinterpret_cast<uint4*>(dstp + 8) = s1;
    }
}

// ---------------------------------------------------------------------------
// MHA via bf16 MFMA 32x32x16, split-K. One wave = 32 q-rows of one head.
// S^T[key][q] = K·Q^T (4 MFMAs, d=64). Lane holds 16 P-values of ONE q-col
// -> in-lane softmax reduce + 1 permlane32_swap half-exchange (order-robust
// fmax/add of both returns). P->B-frag repack: 8 cvt_pk + 4 permlane32_swap
// (all VALU pipe, no DS bpermute). PV: O^T = V^T·P^T (4 MFMAs).
// ---------------------------------------------------------------------------
__launch_bounds__(256)
__global__ void mha_mfma_kernel(const unsigned short* __restrict__ qkv_bf, // [N][768]
                                const unsigned short* __restrict__ vt_bf,  // [256][N]
                                float* __restrict__ opart,  // [MSPLIT][N][256]
                                float* __restrict__ mpart,  // [MSPLIT][NHEAD][N]
                                float* __restrict__ lpart,  // [MSPLIT][NHEAD][N]
                                int N)
{
    const int lane = threadIdx.x & 63;
    const int l31 = lane & 31;
    const int hi = lane >> 5;
    const int gw = blockIdx.x * 4 + (threadIdx.x >> 6);
    const int split = gw & (MSPLIT - 1);
    const int gq = gw / MSPLIT;         // head * (N/32) + qtile
    const int h = gq >> 7;              // N/32 = 128 qtiles per head (N=4096)
    const int qt = gq & 127;
    const int q0 = qt * 32;
    const int kbeg = split * (N / MSPLIT);
    const int kend = kbeg + (N / MSPLIT);

    // Q B-frags: col=q0+l31, k-octet d = 16j + hi*8 + {0..7}
    B8 qf0, qf1, qf2, qf3;
    {
        const unsigned short* qp = qkv_bf + (size_t)(q0 + l31) * 768 + h * 64 + hi * 8;
        qf0.u = *reinterpret_cast<const uint4*>(qp);
        qf1.u = *reinterpret_cast<const uint4*>(qp + 16);
        qf2.u = *reinterpret_cast<const uint4*>(qp + 32);
        qf3.u = *reinterpret_cast<const uint4*>(qp + 48);
    }

    f32x16 o0, o1;
#pragma unroll
    for (int i = 0; i < 16; ++i) { o0[i] = 0.f; o1[i] = 0.f; }
    float m_run = -1e30f, l_run = 0.f;

    const unsigned short* kbase = qkv_bf + 256 + h * 64 + hi * 8;
    const unsigned short* vbase = vt_bf + (size_t)(h * 64 + l31) * N + hi * 8;

    for (int ck = kbeg; ck < kend; ck += 32) {
        // ---- K A-frags: row=ck+l31 (key), k-octet d = 16j + hi*8 ----
        const unsigned short* kp = kbase + (size_t)(ck + l31) * 768;
        B8 kf0, kf1, kf2, kf3;
        kf0.u = *reinterpret_cast<const uint4*>(kp);
        kf1.u = *reinterpret_cast<const uint4*>(kp + 16);
        kf2.u = *reinterpret_cast<const uint4*>(kp + 32);
        kf3.u = *reinterpret_cast<const uint4*>(kp + 48);
        // ---- V^T A-frags issued early: row=d-tile + l31, k = keys ----
        const unsigned short* vp = vbase + ck;
        B8 vf00, vf01, vf10, vf11;
        vf00.u = *reinterpret_cast<const uint4*>(vp);
        vf01.u = *reinterpret_cast<const uint4*>(vp + 16);
        vf10.u = *reinterpret_cast<const uint4*>(vp + (size_t)32 * N);
        vf11.u = *reinterpret_cast<const uint4*>(vp + (size_t)32 * N + 16);

        // ---- S^T = K·Q^T over d=64 ----
        f32x16 s;
#pragma unroll
        for (int i = 0; i < 16; ++i) s[i] = 0.f;
        s = __builtin_amdgcn_mfma_f32_32x32x16_bf16(kf0.v, qf0.v, s, 0, 0, 0);
        s = __builtin_amdgcn_mfma_f32_32x32x16_bf16(kf1.v, qf1.v, s, 0, 0, 0);
        s = __builtin_amdgcn_mfma_f32_32x32x16_bf16(kf2.v, qf2.v, s, 0, 0, 0);
        s = __builtin_amdgcn_mfma_f32_32x32x16_bf16(kf3.v, qf3.v, s, 0, 0, 0);

        // ---- in-lane max over 16 keys, half-exchange, scale ----
        float mx = s[0];
#pragma unroll
        for (int i = 1; i < 16; ++i) mx = fmaxf(mx, s[i]);
        mx *= 0.125f;
        {
            uint2v mr = plswap_(__float_as_uint(mx), __float_as_uint(mx));
            mx = fmaxf(__uint_as_float(mr[0]), __uint_as_float(mr[1]));   // order-robust
        }
        const float mnew = fmaxf(m_run, mx);
        const float f = __expf(m_run - mnew);
        m_run = mnew;

        // ---- exp (scale folded), partial sum (per-half; combined at end) ----
        float p[16];
        float sum = 0.f;
#pragma unroll
        for (int i = 0; i < 16; ++i) {
            p[i] = __expf(fmaf(s[i], 0.125f, -mnew));
            sum += p[i];
        }
        l_run = l_run * f + sum;
        o0 *= f;
        o1 *= f;

        // ---- repack P (C-layout rows) -> two B-frags via cvt_pk + permlane ----
        unsigned int w0 = cvtpk_(p[0], p[1]),  w1 = cvtpk_(p[2], p[3]);
        unsigned int w2 = cvtpk_(p[4], p[5]),  w3 = cvtpk_(p[6], p[7]);
        unsigned int w4 = cvtpk_(p[8], p[9]),  w5 = cvtpk_(p[10], p[11]);
        unsigned int w6 = cvtpk_(p[12], p[13]), w7 = cvtpk_(p[14], p[15]);
        uint2v r02 = plswap_(w0, w2);
        uint2v r13 = plswap_(w1, w3);
        uint2v r46 = plswap_(w4, w6);
        uint2v r57 = plswap_(w5, w7);
        B8 pb0, pb1;
        pb0.u = (uint4){r02[0], r13[0], r02[1], r13[1]};   // keys ck+0..15
        pb1.u = (uint4){r46[0], r57[0], r46[1], r57[1]};   // keys ck+16..31

        // ---- O^T += V^T·P^T ----
        o0 = __builtin_amdgcn_mfma_f32_32x32x16_bf16(vf00.v, pb0.v, o0, 0, 0, 0);
        o0 = __builtin_amdgcn_mfma_f32_32x32x16_bf16(vf01.v, pb1.v, o0, 0, 0, 0);
        o1 = __builtin_amdgcn_mfma_f32_32x32x16_bf16(vf10.v, pb0.v, o1, 0, 0, 0);
        o1 = __builtin_amdgcn_mfma_f32_32x32x16_bf16(vf11.v, pb1.v, o1, 0, 0, 0);
    }

    // combine l across halves (m already combined per chunk)
    {
        uint2v lr = plswap_(__float_as_uint(l_run), __float_as_uint(l_run));
        l_run = __uint_as_float(lr[0]) + __uint_as_float(lr[1]);          // order-robust
    }

    // write raw O numerator: lane (q=q0+l31) holds d = dt*32 + (reg&3)+8*(reg>>2)+4*hi
    float* op = opart + ((size_t)split * N + q0 + l31) * 256 + h * 64 + 4 * hi;
#pragma unroll
    for (int u = 0; u < 4; ++u) {
        float4 s0_ = {o0[4 * u + 0], o0[4 * u + 1], o0[4 * u + 2], o0[4 * u + 3]};
        *reinterpret_cast<float4*>(op + 8 * u) = s0_;
        float4 s1_ = {o1[4 * u + 0], o1[4 * u + 1], o1[4 * u + 2], o1[4 * u + 3]};
        *reinterpret_cast<float4*>(op + 32 + 8 * u) = s1_;
    }
    if (hi == 0) {
        mpart[((size_t)split * NHEAD + h) * N + q0 + l31] = m_run;
        lpart[((size_t)split * NHEAD + h) * N + q0 + l31] = l_run;
    }
}

// Combine the MSPLIT partials -> att_o in bf16 (feeds the mha-out bgemm).
__launch_bounds__(256)
__global__ void mha_combine_kernel(const float* __restrict__ opart,
                                   const float* __restrict__ mpart,
                                   const float* __restrict__ lpart,
                                   unsigned short* __restrict__ outpb, int N)
{
    const int q = blockIdx.x;
    const int c = threadIdx.x;
    const int h = c >> 6;
    const size_t base = (size_t)q * 256 + c;
    float m[MSPLIT], l[MSPLIT];
    float M = -1e30f;
#pragma unroll
    for (int s = 0; s < MSPLIT; ++s) {
        m[s] = mpart[(size_t)(s * NHEAD + h) * N + q];
        l[s] = lpart[(size_t)(s * NHEAD + h) * N + q];
        M = fmaxf(M, m[s]);
    }
    float L = 0.f, o = 0.f;
#pragma unroll
    for (int s = 0; s < MSPLIT; ++s) {
        const float w = __expf(m[s] - M);
        L += w * l[s];
        o = fmaf(w, opart[(size_t)s * N * 256 + base], o);
    }
    outpb[base] = f2bf(o / L);
}

// ---------------------------------------------------------------------------
// h_ent = LN(0.9*h_ent + 0.1*h_glob); rel = sigmoid(h_ent . q). Wave per row.
// ---------------------------------------------------------------------------
__launch_bounds__(256)
__global__ void mix_ln_rel_kernel(float* __restrict__ he, const float* __restrict__ hg,
                                  const float* __restrict__ g, const float* __restrict__ b,
                                  const float* __restrict__ q, float* __restrict__ rel)
{
    const int row = (blockIdx.x * 256 + threadIdx.x) >> 6;
    const int lane = threadIdx.x & 63;
    const float4 a = *reinterpret_cast<const float4*>(&he[(size_t)row * 256 + (lane << 2)]);
    const float4 c = *reinterpret_cast<const float4*>(&hg[(size_t)row * 256 + (lane << 2)]);
    float4 v;
    v.x = 0.9f * a.x + 0.1f * c.x; v.y = 0.9f * a.y + 0.1f * c.y;
    v.z = 0.9f * a.z + 0.1f * c.z; v.w = 0.9f * a.w + 0.1f * c.w;
    const float mean = wave_sum64(v.x + v.y + v.z + v.w) * (1.f / 256.f);
    float4 d = {v.x - mean, v.y - mean, v.z - mean, v.w - mean};
    const float var = wave_sum64(d.x * d.x + d.y * d.y + d.z * d.z + d.w * d.w) * (1.f / 256.f);
    const float rs = rsqrtf(var + 1e-5f);
    const float4 gg = *reinterpret_cast<const float4*>(&g[lane << 2]);
    const float4 bb = *reinterpret_cast<const float4*>(&b[lane << 2]);
    float4 y = {d.x * rs * gg.x + bb.x, d.y * rs * gg.y + bb.y,
                d.z * rs * gg.z + bb.z, d.w * rs * gg.w + bb.w};
    *reinterpret_cast<float4*>(&he[(size_t)row * 256 + (lane << 2)]) = y;
    const float4 qq = *reinterpret_cast<const float4*>(&q[lane << 2]);
    const float dq = wave_sum64(y.x * qq.x + y.y * qq.y + y.z * qq.z + y.w * qq.w);
    if (lane == 0) rel[row] = sigmoidf_(dq);
}

// ctx[p] = sum_{e in seg(p)} h_ent[src]*rel[src]. Wave per (p, quarter).
__launch_bounds__(256)
__global__ void ctx_gather_kernel(const float* __restrict__ he, const float* __restrict__ rel,
                                  const int* __restrict__ indptr, const int* __restrict__ ssrc,
                                  float* __restrict__ ctx)
{
    const int gw = (blockIdx.x * 256 + threadIdx.x) >> 6;
    const int lane = threadIdx.x & 63;
    const int p = gw >> 2, qt = gw & 3;
    const int e0 = indptr[p], e1 = indptr[p + 1];
    float acc = 0.f;
    for (int e = e0; e < e1; ++e) {
        const int sr = ssrc[e];
        acc = fmaf(he[(size_t)sr * 256 + qt * 64 + lane], rel[sr], acc);
    }
    ctx[(size_t)p * 256 + qt * 64 + lane] = acc;
}

// h_psg = LN(h_psg + ctx). Wave per row.
__launch_bounds__(256)
__global__ void psg_ln_kernel(float* __restrict__ hp, const float* __restrict__ ctx,
                              const float* __restrict__ g, const float* __restrict__ b)
{
    const int row = (blockIdx.x * 256 + threadIdx.x) >> 6;
    const int lane = threadIdx.x & 63;
    const float4 a = *reinterpret_cast<const float4*>(&hp[(size_t)row * 256 + (lane << 2)]);
    const float4 c = *reinterpret_cast<const float4*>(&ctx[(size_t)row * 256 + (lane << 2)]);
    float4 v = {a.x + c.x, a.y + c.y, a.z + c.z, a.w + c.w};
    const float mean = wave_sum64(v.x + v.y + v.z + v.w) * (1.f / 256.f);
    float4 d = {v.x - mean, v.y - mean, v.z - mean, v.w - mean};
    const float var = wave_sum64(d.x * d.x + d.y * d.y + d.z * d.z + d.w * d.w) * (1.f / 256.f);
    const float rs = rsqrtf(var + 1e-5f);
    const float4 gg = *reinterpret_cast<const float4*>(&g[lane << 2]);
    const float4 bb = *reinterpret_cast<const float4*>(&b[lane << 2]);
    float4 y = {d.x * rs * gg.x + bb.x, d.y * rs * gg.y + bb.y,
                d.z * rs * gg.z + bb.z, d.w * rs * gg.w + bb.w};
    *reinterpret_cast<float4*>(&hp[(size_t)row * 256 + (lane << 2)]) = y;
}

// qterm[j] = b1[j] + w1[j, 256:512] . q
__global__ void qterm_kernel(const float* __restrict__ w1, const float* __restrict__ b1,
                             const float* __restrict__ q, float* __restrict__ qterm)
{
    __shared__ float qs[256];
    const int t = threadIdx.x;
    qs[t] = q[t];
    __syncthreads();
    float s = b1[t];
    for (int k = 0; k < 256; ++k) s = fmaf(w1[(size_t)t * 512 + 256 + k], qs[k], s);
    qterm[t] = s;
}

// ---------------------------------------------------------------------------
extern "C" void kernel_launch(void* const* d_in, const int* in_sizes, int n_in,
                              void* d_out, int out_size, void* d_ws, size_t ws_size,
                              hipStream_t stream)
{
    const float* x_ent = (const float*)d_in[0];
    const float* x_psg = (const float*)d_in[1];
    const float* q_emb = (const float*)d_in[2];
    const float* Wk_e = (const float*)d_in[3];  const float* bk_e = (const float*)d_in[4];
    const float* Wq_e = (const float*)d_in[5];  const float* bq_e = (const float*)d_in[6];
    const float* Wv_e = (const float*)d_in[7];  const float* bv_e = (const float*)d_in[8];
    const float* Wo_e = (const float*)d_in[9];  const float* bo_e = (const float*)d_in[10];
    const float* sk_e = (const float*)d_in[11];
    const float* Wk_p = (const float*)d_in[12]; const float* bk_p = (const float*)d_in[13];
    const float* Wq_p = (const float*)d_in[14]; const float* bq_p = (const float*)d_in[15];
    const float* Wv_p = (const float*)d_in[16]; const float* bv_p = (const float*)d_in[17];
    const float* Wo_p = (const float*)d_in[18]; const float* bo_p = (const float*)d_in[19];
    const float* sk_p = (const float*)d_in[20];
    const float* a_e2p = (const float*)d_in[21];
    const float* m_e2p = (const float*)d_in[22];
    const float* p_e2p = (const float*)d_in[23];
    const float* a_p2e = (const float*)d_in[24];
    const float* m_p2e = (const float*)d_in[25];
    const float* p_p2e = (const float*)d_in[26];
    const float* Wmi = (const float*)d_in[27];  const float* bmi = (const float*)d_in[28];
    const float* Wmo = (const float*)d_in[29];  const float* bmo = (const float*)d_in[30];
    const float* lng_e = (const float*)d_in[31]; const float* lnb_e = (const float*)d_in[32];
    const float* lng_p = (const float*)d_in[33]; const float* lnb_p = (const float*)d_in[34];
    const float* w1 = (const float*)d_in[35];   const float* b1 = (const float*)d_in[36];
    const float* w2 = (const float*)d_in[37];   const float* b2 = (const float*)d_in[38];
    const int* e2p_src = (const int*)d_in[39];
    const int* e2p_dst = (const int*)d_in[40];
    const int* p2e_src = (const int*)d_in[41];
    const int* p2e_dst = (const int*)d_in[42];

    const int NE = in_sizes[0] / DIM;
    const int NP = in_sizes[1] / DIM;
    const int E  = in_sizes[39];
    float* scores = (float*)d_out;

    char* wp = (char*)d_ws;
    auto alloc = [&](size_t bytes) -> void* {
        void* r = (void*)wp;
        wp += (bytes + 255) & ~(size_t)255;
        return r;
    };
    float* kqv_e = (float*)alloc((size_t)NE * 768 * 4);
    float* kqv_p = (float*)alloc((size_t)NP * 768 * 4);
    float* kt_e  = (float*)alloc((size_t)NE * 256 * 4);
    float* vt_e  = (float*)alloc((size_t)NE * 256 * 4);
    float* kt_p  = (float*)alloc((size_t)NP * 256 * 4);
    float* vt_p  = (float*)alloc((size_t)NP * 256 * 4);
    float* agg_p = (float*)alloc((size_t)NP * 256 * 4);
    float* agg_e = (float*)alloc((size_t)NE * 256 * 4);
    float* h_ent = (float*)alloc((size_t)NE * 256 * 4);
    float* h_psg = (float*)alloc((size_t)NP * 256 * 4);
    float* h_glob= (float*)alloc((size_t)NE * 256 * 4);
    float* relv  = (float*)alloc((size_t)NE * 4);
    float* ctxb  = (float*)alloc((size_t)NP * 256 * 4);
    float* qterm = (float*)alloc(256 * 4);
    unsigned short* warena  = (unsigned short*)alloc((size_t)12 * 65536 * 2);
    unsigned short* xe_bf   = (unsigned short*)alloc((size_t)NE * 256 * 2);
    unsigned short* xp_bf   = (unsigned short*)alloc((size_t)NP * 256 * 2);
    unsigned short* ge_bf   = (unsigned short*)alloc((size_t)NE * 256 * 2);
    unsigned short* gp_bf   = (unsigned short*)alloc((size_t)NP * 256 * 2);
    unsigned short* hent_bf = (unsigned short*)alloc((size_t)NE * 256 * 2);
    unsigned short* atto_bf = (unsigned short*)alloc((size_t)NE * 256 * 2);
    unsigned short* qkv_bf  = (unsigned short*)alloc((size_t)NE * 768 * 2);
    unsigned short* vt_bf   = (unsigned short*)alloc((size_t)256 * NE * 2);
    float* mpart = (float*)alloc((size_t)MSPLIT * NHEAD * NE * 4);
    float* lpart = (float*)alloc((size_t)MSPLIT * NHEAD * NE * 4);
    // opart (MSPLIT*NE*256 fp32 = 32 MB) aliases kqv_e..vt_e (33.5 MB contiguous):
    // all four buffers are dead once the hgt_attn dispatches complete,
    // before mha_mfma runs.
    float* opart = kqv_e;
    int* cnt_a = (int*)alloc((size_t)NP * 4);
    int* cur_a = (int*)alloc((size_t)NP * 4);
    int* ip_a  = (int*)alloc((size_t)(NP + 1) * 4);
    int* ss_a  = (int*)alloc((size_t)E * 4);
    int* cnt_b = (int*)alloc((size_t)NE * 4);
    int* cur_b = (int*)alloc((size_t)NE * 4);
    int* ip_b  = (int*)alloc((size_t)(NE + 1) * 4);
    int* ss_b  = (int*)alloc((size_t)E * 4);

    hipMemsetAsync(cnt_a, 0, (size_t)NP * 4, stream);
    hipMemsetAsync(cnt_b, 0, (size_t)NE * 4, stream);
    hipMemsetAsync(d_out, 0, (size_t)out_size * 4, stream);

    // ---- bf16 conversions (weights + inputs) ----
    cvt_w_kernel<<<dim3(32, 12), 256, 0, stream>>>(
        Wk_e, Wq_e, Wv_e, Wo_e, Wk_p, Wq_p, Wv_p, Wo_p,
        Wmi, Wmi + 65536, Wmi + 131072, Wmo, warena);
    cvt_bf16_kernel<0><<<NE * 256 / 2048, 256, 0, stream>>>(x_ent, xe_bf, NE * 32);
    cvt_bf16_kernel<0><<<NP * 256 / 2048, 256, 0, stream>>>(x_psg, xp_bf, NP * 32);

    const int eb = (E + 255) / 256;
    edge_count_kernel<<<eb, 256, 0, stream>>>(e2p_dst, cnt_a, E);
    edge_count_kernel<<<eb, 256, 0, stream>>>(p2e_dst, cnt_b, E);
    scan_kernel<<<1, 1024, 0, stream>>>(cnt_a, ip_a, cur_a);
    scan_kernel<<<1, 1024, 0, stream>>>(cnt_b, ip_b, cur_b);
    edge_scatter_kernel<<<eb, 256, 0, stream>>>(e2p_src, e2p_dst, cur_a, ss_a, E);
    edge_scatter_kernel<<<eb, 256, 0, stream>>>(p2e_src, p2e_dst, cur_b, ss_b, E);

    // HGT k|q|v projections (bf16 MFMA)
    bgemm_kernel<0,1,0><<<dim3(12, NE / 64), 256, 0, stream>>>(
        xe_bf, warena, warena + 65536, warena + 131072, bk_e, bq_e, bv_e,
        kqv_e, 768, nullptr, 0, nullptr, nullptr);
    bgemm_kernel<0,1,0><<<dim3(12, NP / 64), 256, 0, stream>>>(
        xp_bf, warena + 4*65536, warena + 5*65536, warena + 6*65536, bk_p, bq_p, bv_p,
        kqv_p, 768, nullptr, 0, nullptr, nullptr);

    rel_transform_kernel<<<dim3(NE / 64, NHEAD), 256, 0, stream>>>(kqv_e + 0,   768, a_e2p, kt_e);
    rel_transform_kernel<<<dim3(NE / 64, NHEAD), 256, 0, stream>>>(kqv_e + 512, 768, m_e2p, vt_e);
    rel_transform_kernel<<<dim3(NP / 64, NHEAD), 256, 0, stream>>>(kqv_p + 0,   768, a_p2e, kt_p);
    rel_transform_kernel<<<dim3(NP / 64, NHEAD), 256, 0, stream>>>(kqv_p + 512, 768, m_p2e, vt_p);

    hgt_attn_kernel<<<NP / 4, 256, 0, stream>>>(kqv_p + 256, kt_e, vt_e, p_e2p, ip_a, ss_a, agg_p);
    hgt_attn_kernel<<<NE / 4, 256, 0, stream>>>(kqv_e + 256, kt_p, vt_p, p_p2e, ip_b, ss_b, agg_e);

    // HGT out: gelu+cvt, then bf16 MFMA GEMM with sigmoid-skip epilogue
    cvt_bf16_kernel<1><<<NE * 256 / 2048, 256, 0, stream>>>(agg_e, ge_bf, NE * 32);
    cvt_bf16_kernel<1><<<NP * 256 / 2048, 256, 0, stream>>>(agg_p, gp_bf, NP * 32);
    bgemm_kernel<1,1,1><<<dim3(4, NE / 64), 256, 0, stream>>>(
        ge_bf, warena + 3*65536, warena + 3*65536, warena + 3*65536, bo_e, bo_e, bo_e,
        h_ent, 256, hent_bf, 256, x_ent, sk_e);
    bgemm_kernel<1,1,0><<<dim3(4, NP / 64), 256, 0, stream>>>(
        gp_bf, warena + 7*65536, warena + 7*65536, warena + 7*65536, bo_p, bo_p, bo_p,
        h_psg, 256, nullptr, 0, x_psg, sk_p);

    // MHA: qkv projection (bf16-only out), V-transpose, split-K 32x32 MFMA flash,
    // combine (bf16 out), out projection
    bgemm_kernel<0,0,1><<<dim3(12, NE / 64), 256, 0, stream>>>(
        hent_bf, warena + 8*65536, warena + 9*65536, warena + 10*65536,
        bmi, bmi + 256, bmi + 512,
        nullptr, 0, qkv_bf, 768, nullptr, nullptr);
    vtrans_kernel<<<dim3(NE / 64, NHEAD), 256, 0, stream>>>(qkv_bf, vt_bf, NE);
    mha_mfma_kernel<<<NHEAD * (NE / 32) * MSPLIT / 4, 256, 0, stream>>>(
        qkv_bf, vt_bf, opart, mpart, lpart, NE);
    mha_combine_kernel<<<NE, 256, 0, stream>>>(opart, mpart, lpart, atto_bf, NE);
    bgemm_kernel<0,1,0><<<dim3(4, NE / 64), 256, 0, stream>>>(
        atto_bf, warena + 11*65536, warena + 11*65536, warena + 11*65536, bmo, bmo, bmo,
        h_glob, 256, nullptr, 0, nullptr, nullptr);

    mix_ln_rel_kernel<<<NE / 4, 256, 0, stream>>>(h_ent, h_glob, lng_e, lnb_e, q_emb, relv);

    ctx_gather_kernel<<<NP, 256, 0, stream>>>(h_ent, relv, ip_a, ss_a, ctxb);
    psg_ln_kernel<<<NP / 4, 256, 0, stream>>>(h_psg, ctxb, lng_p, lnb_p);

    // scoring head (kept fp32)
    qterm_kernel<<<1, 256, 0, stream>>>(w1, b1, q_emb, qterm);
    gemm_kernel<0,2><<<dim3(4, NP / 64), 256, 0, stream>>>(
        h_psg, 256, w1, w1, w1, 512, qterm, qterm, qterm,
        nullptr, 256, 256, scores, w2, b2);
}

// Round 11
// 666.954 us; speedup vs baseline: 1.0778x; 1.0102x over previous
//
#include <hip/hip_runtime.h>
#include <hip/hip_bf16.h>
#include <math.h>

#define DIM 256
#define NHEAD 4
#define HD 64
#define MSPLIT 8

typedef __attribute__((ext_vector_type(8))) short short8b;   // 8 bf16 (4 VGPRs)
typedef __attribute__((ext_vector_type(4))) float f32x4;
typedef __attribute__((ext_vector_type(16))) float f32x16;
typedef __attribute__((ext_vector_type(2))) unsigned int uint2v;

union B8 { uint4 u; short8b v; };

__device__ __forceinline__ float sigmoidf_(float x) { return 1.0f / (1.0f + __expf(-x)); }
__device__ __forceinline__ float geluf_(float x) {
    return 0.5f * x * (1.0f + erff(x * 0.70710678118654752440f));
}
__device__ __forceinline__ float wave_sum64(float v) {
    v += __shfl_xor(v, 32); v += __shfl_xor(v, 16); v += __shfl_xor(v, 8);
    v += __shfl_xor(v, 4);  v += __shfl_xor(v, 2);  v += __shfl_xor(v, 1);
    return v;
}
__device__ __forceinline__ unsigned short f2bf(float f) {   // RNE f32->bf16 bits
    union { float f; unsigned int u; } a; a.f = f;
    unsigned int u = a.u;
    unsigned int r = (u + 0x7FFFu + ((u >> 16) & 1u)) >> 16;
    return (unsigned short)r;
}
// single-instruction packed f32x2 -> bf16x2 (no builtin on gfx950; guide T12)
__device__ __forceinline__ unsigned int cvtpk_(float lo, float hi) {
    unsigned int r;
    asm("v_cvt_pk_bf16_f32 %0, %1, %2" : "=v"(r) : "v"(lo), "v"(hi));
    return r;
}
// permlane32_swap: r[0] = {a.lanes0-31, b.lanes0-31}, r[1] = {a.lanes32-63, b.lanes32-63}
__device__ __forceinline__ uint2v plswap_(unsigned int a, unsigned int b) {
    return __builtin_amdgcn_permlane32_swap(a, b, false, false);
}

// ---------------------------------------------------------------------------
// fp32 -> bf16 conversion passes (8 elems/thread). GELU variant for agg.
// ---------------------------------------------------------------------------
template<int DO_GELU>
__launch_bounds__(256)
__global__ void cvt_bf16_kernel(const float* __restrict__ src,
                                unsigned short* __restrict__ dst, int n8)
{
    const int i = blockIdx.x * 256 + threadIdx.x;
    if (i >= n8) return;
    float4 a = reinterpret_cast<const float4*>(src)[2 * i];
    float4 b = reinterpret_cast<const float4*>(src)[2 * i + 1];
    if (DO_GELU) {
        a.x = geluf_(a.x); a.y = geluf_(a.y); a.z = geluf_(a.z); a.w = geluf_(a.w);
        b.x = geluf_(b.x); b.y = geluf_(b.y); b.z = geluf_(b.z); b.w = geluf_(b.w);
    }
    ushort4 lo = {f2bf(a.x), f2bf(a.y), f2bf(a.z), f2bf(a.w)};
    ushort4 hi = {f2bf(b.x), f2bf(b.y), f2bf(b.z), f2bf(b.w)};
    reinterpret_cast<ushort4*>(dst)[2 * i] = lo;
    reinterpret_cast<ushort4*>(dst)[2 * i + 1] = hi;
}

// 12 weight chunks of 256x256 fp32 -> bf16 arena. blockIdx.y = chunk.
__launch_bounds__(256)
__global__ void cvt_w_kernel(const float* __restrict__ W0, const float* __restrict__ W1,
                             const float* __restrict__ W2, const float* __restrict__ W3,
                             const float* __restrict__ W4, const float* __restrict__ W5,
                             const float* __restrict__ W6, const float* __restrict__ W7,
                             const float* __restrict__ W8, const float* __restrict__ W9,
                             const float* __restrict__ W10, const float* __restrict__ W11,
                             unsigned short* __restrict__ arena)
{
    const float* s;
    switch (blockIdx.y) {
        case 0: s = W0; break;  case 1: s = W1; break;  case 2: s = W2; break;
        case 3: s = W3; break;  case 4: s = W4; break;  case 5: s = W5; break;
        case 6: s = W6; break;  case 7: s = W7; break;  case 8: s = W8; break;
        case 9: s = W9; break;  case 10: s = W10; break; default: s = W11; break;
    }
    const int i = blockIdx.x * 256 + threadIdx.x;   // 32 blocks x 256 thr x 8 = 65536
    unsigned short* dst = arena + (size_t)blockIdx.y * 65536;
    float4 a = reinterpret_cast<const float4*>(s)[2 * i];
    float4 b = reinterpret_cast<const float4*>(s)[2 * i + 1];
    ushort4 lo = {f2bf(a.x), f2bf(a.y), f2bf(a.z), f2bf(a.w)};
    ushort4 hi = {f2bf(b.x), f2bf(b.y), f2bf(b.z), f2bf(b.w)};
    reinterpret_cast<ushort4*>(dst)[2 * i] = lo;
    reinterpret_cast<ushort4*>(dst)[2 * i + 1] = hi;
}

// ---------------------------------------------------------------------------
// bf16 MFMA GEMM: C[M,Nout] = epilogue( Abf[M,256] @ Wbf^T + bias ).
// ---------------------------------------------------------------------------
template<int OUT_MODE, int WF32, int WBF>
__launch_bounds__(256)
__global__ void bgemm_kernel(const unsigned short* __restrict__ Abf,
                             const unsigned short* __restrict__ W0b,
                             const unsigned short* __restrict__ W1b,
                             const unsigned short* __restrict__ W2b,
                             const float* __restrict__ B0, const float* __restrict__ B1,
                             const float* __restrict__ B2,
                             float* __restrict__ C, int ldc,
                             unsigned short* __restrict__ Cbf, int ldcb,
                             const float* __restrict__ xres,
                             const float* __restrict__ skipv)
{
    const int t = threadIdx.x;
    const int lane = t & 63;
    const int wid = t >> 6;
    const int col16 = lane & 15;
    const int oct = lane >> 4;
    const int r0 = blockIdx.y * 64 + wid * 16;
    const int c0 = blockIdx.x * 64;
    const int widx = c0 >> 8;
    const unsigned short* W = (widx == 0) ? W0b : (widx == 1 ? W1b : W2b);
    const float* Bv = (widx == 0) ? B0 : (widx == 1 ? B1 : B2);
    const int cw = c0 & 255;

    const unsigned short* aptr = Abf + (size_t)(r0 + col16) * 256 + oct * 8;
    const unsigned short* wptr = W + (size_t)(cw + col16) * 256 + oct * 8;

    f32x4 acc0 = {0,0,0,0}, acc1 = {0,0,0,0}, acc2 = {0,0,0,0}, acc3 = {0,0,0,0};
#pragma unroll
    for (int k0 = 0; k0 < 256; k0 += 32) {
        B8 af, w0, w1, w2, w3;
        af.u = *reinterpret_cast<const uint4*>(aptr + k0);
        w0.u = *reinterpret_cast<const uint4*>(wptr + k0);
        w1.u = *reinterpret_cast<const uint4*>(wptr + k0 + 16 * 256);
        w2.u = *reinterpret_cast<const uint4*>(wptr + k0 + 32 * 256);
        w3.u = *reinterpret_cast<const uint4*>(wptr + k0 + 48 * 256);
        acc0 = __builtin_amdgcn_mfma_f32_16x16x32_bf16(af.v, w0.v, acc0, 0, 0, 0);
        acc1 = __builtin_amdgcn_mfma_f32_16x16x32_bf16(af.v, w1.v, acc1, 0, 0, 0);
        acc2 = __builtin_amdgcn_mfma_f32_16x16x32_bf16(af.v, w2.v, acc2, 0, 0, 0);
        acc3 = __builtin_amdgcn_mfma_f32_16x16x32_bf16(af.v, w3.v, acc3, 0, 0, 0);
    }

    float bias[4];
#pragma unroll
    for (int j = 0; j < 4; ++j) bias[j] = Bv[cw + j * 16 + col16];
    float sg = 0.f;
    if (OUT_MODE == 1) sg = sigmoidf_(skipv[0]);

    const float av[4][4] = {
        {acc0.x, acc0.y, acc0.z, acc0.w}, {acc1.x, acc1.y, acc1.z, acc1.w},
        {acc2.x, acc2.y, acc2.z, acc2.w}, {acc3.x, acc3.y, acc3.z, acc3.w}};
#pragma unroll
    for (int r = 0; r < 4; ++r) {
        const int row = r0 + oct * 4 + r;
#pragma unroll
        for (int j = 0; j < 4; ++j) {
            const int col = c0 + j * 16 + col16;
            float v = av[j][r] + bias[j];
            if (OUT_MODE == 1) {
                const float xv = xres[(size_t)row * ldc + col];
                v = sg * v + (1.f - sg) * xv;
            }
            if (WF32) C[(size_t)row * ldc + col] = v;
            if (WBF)  Cbf[(size_t)row * ldcb + col] = f2bf(v);
        }
    }
}

// ---------------------------------------------------------------------------
// fp32 GEMM (kept for the scoring head only).
// ---------------------------------------------------------------------------
template<int IN_GELU, int OUT_MODE>
__launch_bounds__(256)
__global__ void gemm_kernel(const float* __restrict__ A, int lda,
                            const float* __restrict__ W0, const float* __restrict__ W1,
                            const float* __restrict__ W2, int ldw,
                            const float* __restrict__ B0, const float* __restrict__ B1,
                            const float* __restrict__ B2,
                            float* __restrict__ C, int ldc, int Kin,
                            float* __restrict__ scores,
                            const float* __restrict__ w2v,
                            const float* __restrict__ b2v)
{
    __shared__ float As[16][68];
    __shared__ float Ws[16][68];
    const int t = threadIdx.x;
    const int r0 = blockIdx.y * 64;
    const int c0 = blockIdx.x * 64;
    const int widx = c0 >> 8;
    const float* W  = (widx == 0) ? W0 : (widx == 1 ? W1 : W2);
    const float* Bv = (widx == 0) ? B0 : (widx == 1 ? B1 : B2);
    const int cw = c0 & 255;

    const int lrow = t >> 2;
    const int lk   = (t & 3) << 2;
    const int ty = t >> 4, tx = t & 15;

    const float* Aptr = A + (size_t)(r0 + lrow) * lda + lk;
    const float* Wptr = W + (size_t)(cw + lrow) * ldw + lk;

    float acc[4][4] = {};
    for (int k0 = 0; k0 < Kin; k0 += 16) {
        float4 av = *reinterpret_cast<const float4*>(Aptr + k0);
        float4 wv = *reinterpret_cast<const float4*>(Wptr + k0);
        if (IN_GELU) {
            av.x = geluf_(av.x); av.y = geluf_(av.y);
            av.z = geluf_(av.z); av.w = geluf_(av.w);
        }
        As[lk + 0][lrow] = av.x; As[lk + 1][lrow] = av.y;
        As[lk + 2][lrow] = av.z; As[lk + 3][lrow] = av.w;
        Ws[lk + 0][lrow] = wv.x; Ws[lk + 1][lrow] = wv.y;
        Ws[lk + 2][lrow] = wv.z; Ws[lk + 3][lrow] = wv.w;
        __syncthreads();
#pragma unroll
        for (int k = 0; k < 16; ++k) {
            const float4 a = *reinterpret_cast<const float4*>(&As[k][ty << 2]);
            const float4 b = *reinterpret_cast<const float4*>(&Ws[k][tx << 2]);
            const float ar[4] = {a.x, a.y, a.z, a.w};
            const float br[4] = {b.x, b.y, b.z, b.w};
#pragma unroll
            for (int i = 0; i < 4; ++i)
#pragma unroll
                for (int j = 0; j < 4; ++j)
                    acc[i][j] = fmaf(ar[i], br[j], acc[i][j]);
        }
        __syncthreads();
    }

    float bias[4];
#pragma unroll
    for (int j = 0; j < 4; ++j) bias[j] = Bv[cw + (tx << 2) + j];

    if (OUT_MODE == 0) {
#pragma unroll
        for (int i = 0; i < 4; ++i) {
            float4 st;
            st.x = acc[i][0] + bias[0]; st.y = acc[i][1] + bias[1];
            st.z = acc[i][2] + bias[2]; st.w = acc[i][3] + bias[3];
            *reinterpret_cast<float4*>(&C[(size_t)(r0 + (ty << 2) + i) * ldc + c0 + (tx << 2)]) = st;
        }
    } else {
        float wv[4];
#pragma unroll
        for (int j = 0; j < 4; ++j) wv[j] = w2v[c0 + (tx << 2) + j];
#pragma unroll
        for (int i = 0; i < 4; ++i) {
            float p = 0.f;
#pragma unroll
            for (int j = 0; j < 4; ++j)
                p = fmaf(fmaxf(acc[i][j] + bias[j], 0.f), wv[j], p);
            if (c0 == 0 && tx == 0) p += b2v[0];
            atomicAdd(&scores[r0 + (ty << 2) + i], p);
        }
    }
}

// ---------------------------------------------------------------------------
// kt[n, h*64+e] = sum_d kin[n, h*64+d] * arel[h, d, e]      (per-head 64x64)
// ---------------------------------------------------------------------------
__launch_bounds__(256)
__global__ void rel_transform_kernel(const float* __restrict__ kin, int ldin,
                                     const float* __restrict__ arel,
                                     float* __restrict__ kout)
{
    __shared__ float Al[64][68];   // [d][e]
    __shared__ float Kl[64][65];   // [r][d]
    const int t = threadIdx.x;
    const int r0 = blockIdx.x * 64;
    const int h = blockIdx.y;
    const float* ah = arel + h * 4096;
    for (int i = t; i < 1024; i += 256) {
        const int rr = i >> 4, c4 = (i & 15) << 2;
        const float4 av = *reinterpret_cast<const float4*>(&ah[rr * 64 + c4]);
        *reinterpret_cast<float4*>(&Al[rr][c4]) = av;
        const float4 kv = *reinterpret_cast<const float4*>(&kin[(size_t)(r0 + rr) * ldin + h * 64 + c4]);
        Kl[rr][c4 + 0] = kv.x; Kl[rr][c4 + 1] = kv.y;
        Kl[rr][c4 + 2] = kv.z; Kl[rr][c4 + 3] = kv.w;
    }
    __syncthreads();
    const int r  = t & 63;
    const int e0 = (t >> 6) << 4;
    float acc[16] = {};
    for (int d = 0; d < 64; ++d) {
        const float kv = Kl[r][d];
#pragma unroll
        for (int u4 = 0; u4 < 4; ++u4) {
            const float4 a = *reinterpret_cast<const float4*>(&Al[d][e0 + (u4 << 2)]);
            acc[u4 * 4 + 0] = fmaf(kv, a.x, acc[u4 * 4 + 0]);
            acc[u4 * 4 + 1] = fmaf(kv, a.y, acc[u4 * 4 + 1]);
            acc[u4 * 4 + 2] = fmaf(kv, a.z, acc[u4 * 4 + 2]);
            acc[u4 * 4 + 3] = fmaf(kv, a.w, acc[u4 * 4 + 3]);
        }
    }
#pragma unroll
    for (int u4 = 0; u4 < 4; ++u4) {
        float4 st = {acc[u4 * 4 + 0], acc[u4 * 4 + 1], acc[u4 * 4 + 2], acc[u4 * 4 + 3]};
        *reinterpret_cast<float4*>(&kout[(size_t)(r0 + r) * 256 + h * 64 + e0 + (u4 << 2)]) = st;
    }
}

// --------------------------- CSR build -------------------------------------
__global__ void edge_count_kernel(const int* __restrict__ dst, int* __restrict__ cnt, int E)
{
    const int i = blockIdx.x * 256 + threadIdx.x;
    if (i < E) atomicAdd(&cnt[dst[i]], 1);
}

__launch_bounds__(1024)
__global__ void scan_kernel(const int* __restrict__ cnt, int* __restrict__ indptr,
                            int* __restrict__ cursor)
{
    __shared__ int sh[1024];
    const int t = threadIdx.x;
    const int4 v = *reinterpret_cast<const int4*>(&cnt[t << 2]);
    const int sum = v.x + v.y + v.z + v.w;
    sh[t] = sum;
    __syncthreads();
    for (int off = 1; off < 1024; off <<= 1) {
        int x = 0;
        if (t >= off) x = sh[t - off];
        __syncthreads();
        if (t >= off) sh[t] += x;
        __syncthreads();
    }
    int run = sh[t] - sum;
    const int base = t << 2;
    if (t == 0) indptr[0] = 0;
    cursor[base + 0] = run; run += v.x; indptr[base + 1] = run;
    cursor[base + 1] = run; run += v.y; indptr[base + 2] = run;
    cursor[base + 2] = run; run += v.z; indptr[base + 3] = run;
    cursor[base + 3] = run; run += v.w; indptr[base + 4] = run;
}

__global__ void edge_scatter_kernel(const int* __restrict__ src, const int* __restrict__ dst,
                                    int* __restrict__ cursor, int* __restrict__ ssrc, int E)
{
    const int i = blockIdx.x * 256 + threadIdx.x;
    if (i < E) {
        const int p = atomicAdd(&cursor[dst[i]], 1);
        ssrc[p] = src[i];
    }
}

// ---------------------------------------------------------------------------
// HGT edge softmax-aggregate: ONE wave per dst node, all 4 heads at once,
// one-edge-ahead software prefetch.
// ---------------------------------------------------------------------------
__launch_bounds__(256)
__global__ void hgt_attn_kernel(const float* __restrict__ qdst,   // q section base, ld=768
                                const float* __restrict__ kt,
                                const float* __restrict__ vt,
                                const float* __restrict__ prel,
                                const int* __restrict__ indptr,
                                const int* __restrict__ ssrc,
                                float* __restrict__ agg)
{
    const int n = blockIdx.x * 4 + (threadIdx.x >> 6);
    const int lane = threadIdx.x & 63;
    const int h = lane >> 4;
    const int d4 = (lane & 15) << 2;
    const float4 q = *reinterpret_cast<const float4*>(&qdst[(size_t)n * 768 + h * 64 + d4]);
    const float ps = prel[h] * 0.125f;
    const int e0 = indptr[n], e1 = indptr[n + 1];
    float m = -1e30f, s = 0.f;
    float4 acc = {0.f, 0.f, 0.f, 0.f};
    float4 kc = {0.f, 0.f, 0.f, 0.f}, vc = {0.f, 0.f, 0.f, 0.f};
    if (e0 < e1) {
        const int sr0 = ssrc[e0];
        kc = *reinterpret_cast<const float4*>(&kt[(size_t)sr0 * 256 + h * 64 + d4]);
        vc = *reinterpret_cast<const float4*>(&vt[(size_t)sr0 * 256 + h * 64 + d4]);
    }
    for (int e = e0; e < e1; ++e) {
        const float4 k = kc, v = vc;
        const int nsr = ssrc[(e + 1 < e1) ? (e + 1) : e];   // clamped prefetch
        kc = *reinterpret_cast<const float4*>(&kt[(size_t)nsr * 256 + h * 64 + d4]);
        vc = *reinterpret_cast<const float4*>(&vt[(size_t)nsr * 256 + h * 64 + d4]);
        float d = q.x * k.x + q.y * k.y + q.z * k.z + q.w * k.w;
        d += __shfl_xor(d, 1); d += __shfl_xor(d, 2);
        d += __shfl_xor(d, 4); d += __shfl_xor(d, 8);
        const float logit = d * ps;
        const float mn = fmaxf(m, logit);
        const float f = __expf(m - mn);
        const float p = __expf(logit - mn);
        s = s * f + p;
        acc.x = acc.x * f + p * v.x;
        acc.y = acc.y * f + p * v.y;
        acc.z = acc.z * f + p * v.z;
        acc.w = acc.w * f + p * v.w;
        m = mn;
    }
    const float inv = 1.f / (s + 1e-16f);
    float4 st = {acc.x * inv, acc.y * inv, acc.z * inv, acc.w * inv};
    *reinterpret_cast<float4*>(&agg[(size_t)n * 256 + h * 64 + d4]) = st;
}

// ---------------------------------------------------------------------------
// V transpose: qkv_bf [N][768] (v section) -> vt[h*64+d][key]  (bf16)
// ---------------------------------------------------------------------------
__launch_bounds__(256)
__global__ void vtrans_kernel(const unsigned short* __restrict__ qkv_bf,
                              unsigned short* __restrict__ vt, int N)
{
    __shared__ unsigned short tile[64][66];
    const int t = threadIdx.x;
    const int k0 = blockIdx.x * 64;
    const int h = blockIdx.y;
    {
        const int key = t >> 2;
        const int d0 = (t & 3) << 4;
        const unsigned short* src = qkv_bf + (size_t)(k0 + key) * 768 + 512 + h * 64 + d0;
        const uint4 a = *reinterpret_cast<const uint4*>(src);
        const uint4 b = *reinterpret_cast<const uint4*>(src + 8);
        const unsigned int w_[8] = {a.x, a.y, a.z, a.w, b.x, b.y, b.z, b.w};
#pragma unroll
        for (int j = 0; j < 8; ++j) {
            tile[d0 + 2 * j][key]     = (unsigned short)(w_[j] & 0xffff);
            tile[d0 + 2 * j + 1][key] = (unsigned short)(w_[j] >> 16);
        }
    }
    __syncthreads();
    {
        const int d = t >> 2;
        const int kk = (t & 3) << 4;
        unsigned int o_[8];
#pragma unroll
        for (int j = 0; j < 8; ++j)
            o_[j] = (unsigned int)tile[d][kk + 2 * j] | ((unsigned int)tile[d][kk + 2 * j + 1] << 16);
        unsigned short* dstp = vt + (size_t)(h * 64 + d) * N + k0 + kk;
        uint4 s0 = {o_[0], o_[1], o_[2], o_[3]};
        uint4 s1 = {o_[4], o_[5], o_[6], o_[7]};
        *reinterpret_cast<uint4*>(dstp) = s0;
        *reinterpret_cast<uint4*>(dstp + 8) = s1;
    }
}

// ---------------------------------------------------------------------------
// MHA via bf16 MFMA 32x32x16, split-K. One wave = 32 q-rows of one head.
// v3: 64 keys/iteration as TWO independent QK chains (sA, sB) -> ONE combined
// softmax pass (halved m/l bookkeeping + o-rescales) with defer-max (T13,
// THR=8: skip rescale when per-iter max doesn't exceed running max by >8).
// Fragment layouts identical to the round-10-verified kernel.
// ---------------------------------------------------------------------------
__launch_bounds__(256)
__global__ void mha_mfma_kernel(const unsigned short* __restrict__ qkv_bf, // [N][768]
                                const unsigned short* __restrict__ vt_bf,  // [256][N]
                                float* __restrict__ opart,  // [MSPLIT][N][256]
                                float* __restrict__ mpart,  // [MSPLIT][NHEAD][N]
                                float* __restrict__ lpart,  // [MSPLIT][NHEAD][N]
                                int N)
{
    const int lane = threadIdx.x & 63;
    const int l31 = lane & 31;
    const int hi = lane >> 5;
    const int gw = blockIdx.x * 4 + (threadIdx.x >> 6);
    const int split = gw & (MSPLIT - 1);
    const int gq = gw / MSPLIT;         // head * (N/32) + qtile
    const int h = gq >> 7;              // N/32 = 128 qtiles per head (N=4096)
    const int qt = gq & 127;
    const int q0 = qt * 32;
    const int kbeg = split * (N / MSPLIT);
    const int kend = kbeg + (N / MSPLIT);

    // Q B-frags: col=q0+l31, k-octet d = 16j + hi*8 + {0..7}
    B8 qf0, qf1, qf2, qf3;
    {
        const unsigned short* qp = qkv_bf + (size_t)(q0 + l31) * 768 + h * 64 + hi * 8;
        qf0.u = *reinterpret_cast<const uint4*>(qp);
        qf1.u = *reinterpret_cast<const uint4*>(qp + 16);
        qf2.u = *reinterpret_cast<const uint4*>(qp + 32);
        qf3.u = *reinterpret_cast<const uint4*>(qp + 48);
    }

    f32x16 o0, o1;
#pragma unroll
    for (int i = 0; i < 16; ++i) { o0[i] = 0.f; o1[i] = 0.f; }
    float m_run = -1e30f, l_run = 0.f;

    const unsigned short* kbase = qkv_bf + 256 + h * 64 + hi * 8;
    const unsigned short* vbase = vt_bf + (size_t)(h * 64 + l31) * N + hi * 8;

    for (int ck = kbeg; ck < kend; ck += 64) {
        // ---- K A-frags: chunk A = keys ck+l31, chunk B = keys ck+32+l31 ----
        const unsigned short* kpA = kbase + (size_t)(ck + l31) * 768;
        const unsigned short* kpB = kbase + (size_t)(ck + 32 + l31) * 768;
        B8 ka0, ka1, ka2, ka3, kb0, kb1, kb2, kb3;
        ka0.u = *reinterpret_cast<const uint4*>(kpA);
        ka1.u = *reinterpret_cast<const uint4*>(kpA + 16);
        ka2.u = *reinterpret_cast<const uint4*>(kpA + 32);
        ka3.u = *reinterpret_cast<const uint4*>(kpA + 48);
        kb0.u = *reinterpret_cast<const uint4*>(kpB);
        kb1.u = *reinterpret_cast<const uint4*>(kpB + 16);
        kb2.u = *reinterpret_cast<const uint4*>(kpB + 32);
        kb3.u = *reinterpret_cast<const uint4*>(kpB + 48);
        // ---- V^T A-frags for 64 keys: d-rows l31 (o0) and 32+l31 (o1) ----
        const unsigned short* vp0 = vbase + ck;
        const unsigned short* vp1 = vbase + (size_t)32 * N + ck;
        B8 va0, va1, va2, va3, vb0, vb1, vb2, vb3;
        va0.u = *reinterpret_cast<const uint4*>(vp0);
        va1.u = *reinterpret_cast<const uint4*>(vp0 + 16);
        va2.u = *reinterpret_cast<const uint4*>(vp0 + 32);
        va3.u = *reinterpret_cast<const uint4*>(vp0 + 48);
        vb0.u = *reinterpret_cast<const uint4*>(vp1);
        vb1.u = *reinterpret_cast<const uint4*>(vp1 + 16);
        vb2.u = *reinterpret_cast<const uint4*>(vp1 + 32);
        vb3.u = *reinterpret_cast<const uint4*>(vp1 + 48);

        // ---- two independent S^T = K·Q^T chains over d=64 ----
        f32x16 sA, sB;
#pragma unroll
        for (int i = 0; i < 16; ++i) { sA[i] = 0.f; sB[i] = 0.f; }
        sA = __builtin_amdgcn_mfma_f32_32x32x16_bf16(ka0.v, qf0.v, sA, 0, 0, 0);
        sB = __builtin_amdgcn_mfma_f32_32x32x16_bf16(kb0.v, qf0.v, sB, 0, 0, 0);
        sA = __builtin_amdgcn_mfma_f32_32x32x16_bf16(ka1.v, qf1.v, sA, 0, 0, 0);
        sB = __builtin_amdgcn_mfma_f32_32x32x16_bf16(kb1.v, qf1.v, sB, 0, 0, 0);
        sA = __builtin_amdgcn_mfma_f32_32x32x16_bf16(ka2.v, qf2.v, sA, 0, 0, 0);
        sB = __builtin_amdgcn_mfma_f32_32x32x16_bf16(kb2.v, qf2.v, sB, 0, 0, 0);
        sA = __builtin_amdgcn_mfma_f32_32x32x16_bf16(ka3.v, qf3.v, sA, 0, 0, 0);
        sB = __builtin_amdgcn_mfma_f32_32x32x16_bf16(kb3.v, qf3.v, sB, 0, 0, 0);

        // ---- combined max over 32 in-lane values + half-exchange ----
        float mx = sA[0];
#pragma unroll
        for (int i = 1; i < 16; ++i) mx = fmaxf(mx, sA[i]);
#pragma unroll
        for (int i = 0; i < 16; ++i) mx = fmaxf(mx, sB[i]);
        mx *= 0.125f;
        {
            uint2v mr = plswap_(__float_as_uint(mx), __float_as_uint(mx));
            mx = fmaxf(__uint_as_float(mr[0]), __uint_as_float(mr[1]));   // order-robust
        }
        // ---- defer-max (T13): skip o-rescale when growth <= 8 ----
        if (!__all(mx <= m_run + 8.0f)) {
            const float mnew = fmaxf(m_run, mx);
            const float f = __expf(m_run - mnew);
            l_run *= f;
            o0 *= f;
            o1 *= f;
            m_run = mnew;
        }

        // ---- exp (scale folded), sum ----
        float p[32];
        float sum = 0.f;
#pragma unroll
        for (int i = 0; i < 16; ++i) {
            p[i] = __expf(fmaf(sA[i], 0.125f, -m_run));
            sum += p[i];
        }
#pragma unroll
        for (int i = 0; i < 16; ++i) {
            p[16 + i] = __expf(fmaf(sB[i], 0.125f, -m_run));
            sum += p[16 + i];
        }
        l_run += sum;

        // ---- repack P -> four B-frags via cvt_pk + permlane (as verified) ----
        unsigned int w0 = cvtpk_(p[0], p[1]),   w1 = cvtpk_(p[2], p[3]);
        unsigned int w2 = cvtpk_(p[4], p[5]),   w3 = cvtpk_(p[6], p[7]);
        unsigned int w4 = cvtpk_(p[8], p[9]),   w5 = cvtpk_(p[10], p[11]);
        unsigned int w6 = cvtpk_(p[12], p[13]), w7 = cvtpk_(p[14], p[15]);
        uint2v r02 = plswap_(w0, w2);
        uint2v r13 = plswap_(w1, w3);
        uint2v r46 = plswap_(w4, w6);
        uint2v r57 = plswap_(w5, w7);
        B8 pb0, pb1, pb2, pb3;
        pb0.u = (uint4){r02[0], r13[0], r02[1], r13[1]};   // keys ck+0..15
        pb1.u = (uint4){r46[0], r57[0], r46[1], r57[1]};   // keys ck+16..31
        unsigned int x0 = cvtpk_(p[16], p[17]), x1 = cvtpk_(p[18], p[19]);
        unsigned int x2 = cvtpk_(p[20], p[21]), x3 = cvtpk_(p[22], p[23]);
        unsigned int x4 = cvtpk_(p[24], p[25]), x5 = cvtpk_(p[26], p[27]);
        unsigned int x6 = cvtpk_(p[28], p[29]), x7 = cvtpk_(p[30], p[31]);
        uint2v q02 = plswap_(x0, x2);
        uint2v q13 = plswap_(x1, x3);
        uint2v q46 = plswap_(x4, x6);
        uint2v q57 = plswap_(x5, x7);
        pb2.u = (uint4){q02[0], q13[0], q02[1], q13[1]};   // keys ck+32..47
        pb3.u = (uint4){q46[0], q57[0], q46[1], q57[1]};   // keys ck+48..63

        // ---- O^T += V^T·P^T over 64 keys ----
        o0 = __builtin_amdgcn_mfma_f32_32x32x16_bf16(va0.v, pb0.v, o0, 0, 0, 0);
        o1 = __builtin_amdgcn_mfma_f32_32x32x16_bf16(vb0.v, pb0.v, o1, 0, 0, 0);
        o0 = __builtin_amdgcn_mfma_f32_32x32x16_bf16(va1.v, pb1.v, o0, 0, 0, 0);
        o1 = __builtin_amdgcn_mfma_f32_32x32x16_bf16(vb1.v, pb1.v, o1, 0, 0, 0);
        o0 = __builtin_amdgcn_mfma_f32_32x32x16_bf16(va2.v, pb2.v, o0, 0, 0, 0);
        o1 = __builtin_amdgcn_mfma_f32_32x32x16_bf16(vb2.v, pb2.v, o1, 0, 0, 0);
        o0 = __builtin_amdgcn_mfma_f32_32x32x16_bf16(va3.v, pb3.v, o0, 0, 0, 0);
        o1 = __builtin_amdgcn_mfma_f32_32x32x16_bf16(vb3.v, pb3.v, o1, 0, 0, 0);
    }

    // combine l across halves (m already combined per chunk)
    {
        uint2v lr = plswap_(__float_as_uint(l_run), __float_as_uint(l_run));
        l_run = __uint_as_float(lr[0]) + __uint_as_float(lr[1]);          // order-robust
    }

    // write raw O numerator: lane (q=q0+l31) holds d = dt*32 + (reg&3)+8*(reg>>2)+4*hi
    float* op = opart + ((size_t)split * N + q0 + l31) * 256 + h * 64 + 4 * hi;
#pragma unroll
    for (int u = 0; u < 4; ++u) {
        float4 s0_ = {o0[4 * u + 0], o0[4 * u + 1], o0[4 * u + 2], o0[4 * u + 3]};
        *reinterpret_cast<float4*>(op + 8 * u) = s0_;
        float4 s1_ = {o1[4 * u + 0], o1[4 * u + 1], o1[4 * u + 2], o1[4 * u + 3]};
        *reinterpret_cast<float4*>(op + 32 + 8 * u) = s1_;
    }
    if (hi == 0) {
        mpart[((size_t)split * NHEAD + h) * N + q0 + l31] = m_run;
        lpart[((size_t)split * NHEAD + h) * N + q0 + l31] = l_run;
    }
}

// Combine the MSPLIT partials -> att_o in bf16 (feeds the mha-out bgemm).
__launch_bounds__(256)
__global__ void mha_combine_kernel(const float* __restrict__ opart,
                                   const float* __restrict__ mpart,
                                   const float* __restrict__ lpart,
                                   unsigned short* __restrict__ outpb, int N)
{
    const int q = blockIdx.x;
    const int c = threadIdx.x;
    const int h = c >> 6;
    const size_t base = (size_t)q * 256 + c;
    float m[MSPLIT], l[MSPLIT];
    float M = -1e30f;
#pragma unroll
    for (int s = 0; s < MSPLIT; ++s) {
        m[s] = mpart[(size_t)(s * NHEAD + h) * N + q];
        l[s] = lpart[(size_t)(s * NHEAD + h) * N + q];
        M = fmaxf(M, m[s]);
    }
    float L = 0.f, o = 0.f;
#pragma unroll
    for (int s = 0; s < MSPLIT; ++s) {
        const float w = __expf(m[s] - M);
        L += w * l[s];
        o = fmaf(w, opart[(size_t)s * N * 256 + base], o);
    }
    outpb[base] = f2bf(o / L);
}

// ---------------------------------------------------------------------------
// h_ent = LN(0.9*h_ent + 0.1*h_glob); rel = sigmoid(h_ent . q). Wave per row.
// ---------------------------------------------------------------------------
__launch_bounds__(256)
__global__ void mix_ln_rel_kernel(float* __restrict__ he, const float* __restrict__ hg,
                                  const float* __restrict__ g, const float* __restrict__ b,
                                  const float* __restrict__ q, float* __restrict__ rel)
{
    const int row = (blockIdx.x * 256 + threadIdx.x) >> 6;
    const int lane = threadIdx.x & 63;
    const float4 a = *reinterpret_cast<const float4*>(&he[(size_t)row * 256 + (lane << 2)]);
    const float4 c = *reinterpret_cast<const float4*>(&hg[(size_t)row * 256 + (lane << 2)]);
    float4 v;
    v.x = 0.9f * a.x + 0.1f * c.x; v.y = 0.9f * a.y + 0.1f * c.y;
    v.z = 0.9f * a.z + 0.1f * c.z; v.w = 0.9f * a.w + 0.1f * c.w;
    const float mean = wave_sum64(v.x + v.y + v.z + v.w) * (1.f / 256.f);
    float4 d = {v.x - mean, v.y - mean, v.z - mean, v.w - mean};
    const float var = wave_sum64(d.x * d.x + d.y * d.y + d.z * d.z + d.w * d.w) * (1.f / 256.f);
    const float rs = rsqrtf(var + 1e-5f);
    const float4 gg = *reinterpret_cast<const float4*>(&g[lane << 2]);
    const float4 bb = *reinterpret_cast<const float4*>(&b[lane << 2]);
    float4 y = {d.x * rs * gg.x + bb.x, d.y * rs * gg.y + bb.y,
                d.z * rs * gg.z + bb.z, d.w * rs * gg.w + bb.w};
    *reinterpret_cast<float4*>(&he[(size_t)row * 256 + (lane << 2)]) = y;
    const float4 qq = *reinterpret_cast<const float4*>(&q[lane << 2]);
    const float dq = wave_sum64(y.x * qq.x + y.y * qq.y + y.z * qq.z + y.w * qq.w);
    if (lane == 0) rel[row] = sigmoidf_(dq);
}

// ctx[p] = sum_{e in seg(p)} h_ent[src]*rel[src]. Wave per (p, quarter).
__launch_bounds__(256)
__global__ void ctx_gather_kernel(const float* __restrict__ he, const float* __restrict__ rel,
                                  const int* __restrict__ indptr, const int* __restrict__ ssrc,
                                  float* __restrict__ ctx)
{
    const int gw = (blockIdx.x * 256 + threadIdx.x) >> 6;
    const int lane = threadIdx.x & 63;
    const int p = gw >> 2, qt = gw & 3;
    const int e0 = indptr[p], e1 = indptr[p + 1];
    float acc = 0.f;
    for (int e = e0; e < e1; ++e) {
        const int sr = ssrc[e];
        acc = fmaf(he[(size_t)sr * 256 + qt * 64 + lane], rel[sr], acc);
    }
    ctx[(size_t)p * 256 + qt * 64 + lane] = acc;
}

// h_psg = LN(h_psg + ctx). Wave per row.
__launch_bounds__(256)
__global__ void psg_ln_kernel(float* __restrict__ hp, const float* __restrict__ ctx,
                              const float* __restrict__ g, const float* __restrict__ b)
{
    const int row = (blockIdx.x * 256 + threadIdx.x) >> 6;
    const int lane = threadIdx.x & 63;
    const float4 a = *reinterpret_cast<const float4*>(&hp[(size_t)row * 256 + (lane << 2)]);
    const float4 c = *reinterpret_cast<const float4*>(&ctx[(size_t)row * 256 + (lane << 2)]);
    float4 v = {a.x + c.x, a.y + c.y, a.z + c.z, a.w + c.w};
    const float mean = wave_sum64(v.x + v.y + v.z + v.w) * (1.f / 256.f);
    float4 d = {v.x - mean, v.y - mean, v.z - mean, v.w - mean};
    const float var = wave_sum64(d.x * d.x + d.y * d.y + d.z * d.z + d.w * d.w) * (1.f / 256.f);
    const float rs = rsqrtf(var + 1e-5f);
    const float4 gg = *reinterpret_cast<const float4*>(&g[lane << 2]);
    const float4 bb = *reinterpret_cast<const float4*>(&b[lane << 2]);
    float4 y = {d.x * rs * gg.x + bb.x, d.y * rs * gg.y + bb.y,
                d.z * rs * gg.z + bb.z, d.w * rs * gg.w + bb.w};
    *reinterpret_cast<float4*>(&hp[(size_t)row * 256 + (lane << 2)]) = y;
}

// qterm[j] = b1[j] + w1[j, 256:512] . q
__global__ void qterm_kernel(const float* __restrict__ w1, const float* __restrict__ b1,
                             const float* __restrict__ q, float* __restrict__ qterm)
{
    __shared__ float qs[256];
    const int t = threadIdx.x;
    qs[t] = q[t];
    __syncthreads();
    float s = b1[t];
    for (int k = 0; k < 256; ++k) s = fmaf(w1[(size_t)t * 512 + 256 + k], qs[k], s);
    qterm[t] = s;
}

// ---------------------------------------------------------------------------
extern "C" void kernel_launch(void* const* d_in, const int* in_sizes, int n_in,
                              void* d_out, int out_size, void* d_ws, size_t ws_size,
                              hipStream_t stream)
{
    const float* x_ent = (const float*)d_in[0];
    const float* x_psg = (const float*)d_in[1];
    const float* q_emb = (const float*)d_in[2];
    const float* Wk_e = (const float*)d_in[3];  const float* bk_e = (const float*)d_in[4];
    const float* Wq_e = (const float*)d_in[5];  const float* bq_e = (const float*)d_in[6];
    const float* Wv_e = (const float*)d_in[7];  const float* bv_e = (const float*)d_in[8];
    const float* Wo_e = (const float*)d_in[9];  const float* bo_e = (const float*)d_in[10];
    const float* sk_e = (const float*)d_in[11];
    const float* Wk_p = (const float*)d_in[12]; const float* bk_p = (const float*)d_in[13];
    const float* Wq_p = (const float*)d_in[14]; const float* bq_p = (const float*)d_in[15];
    const float* Wv_p = (const float*)d_in[16]; const float* bv_p = (const float*)d_in[17];
    const float* Wo_p = (const float*)d_in[18]; const float* bo_p = (const float*)d_in[19];
    const float* sk_p = (const float*)d_in[20];
    const float* a_e2p = (const float*)d_in[21];
    const float* m_e2p = (const float*)d_in[22];
    const float* p_e2p = (const float*)d_in[23];
    const float* a_p2e = (const float*)d_in[24];
    const float* m_p2e = (const float*)d_in[25];
    const float* p_p2e = (const float*)d_in[26];
    const float* Wmi = (const float*)d_in[27];  const float* bmi = (const float*)d_in[28];
    const float* Wmo = (const float*)d_in[29];  const float* bmo = (const float*)d_in[30];
    const float* lng_e = (const float*)d_in[31]; const float* lnb_e = (const float*)d_in[32];
    const float* lng_p = (const float*)d_in[33]; const float* lnb_p = (const float*)d_in[34];
    const float* w1 = (const float*)d_in[35];   const float* b1 = (const float*)d_in[36];
    const float* w2 = (const float*)d_in[37];   const float* b2 = (const float*)d_in[38];
    const int* e2p_src = (const int*)d_in[39];
    const int* e2p_dst = (const int*)d_in[40];
    const int* p2e_src = (const int*)d_in[41];
    const int* p2e_dst = (const int*)d_in[42];

    const int NE = in_sizes[0] / DIM;
    const int NP = in_sizes[1] / DIM;
    const int E  = in_sizes[39];
    float* scores = (float*)d_out;

    char* wp = (char*)d_ws;
    auto alloc = [&](size_t bytes) -> void* {
        void* r = (void*)wp;
        wp += (bytes + 255) & ~(size_t)255;
        return r;
    };
    float* kqv_e = (float*)alloc((size_t)NE * 768 * 4);
    float* kqv_p = (float*)alloc((size_t)NP * 768 * 4);
    float* kt_e  = (float*)alloc((size_t)NE * 256 * 4);
    float* vt_e  = (float*)alloc((size_t)NE * 256 * 4);
    float* kt_p  = (float*)alloc((size_t)NP * 256 * 4);
    float* vt_p  = (float*)alloc((size_t)NP * 256 * 4);
    float* agg_p = (float*)alloc((size_t)NP * 256 * 4);
    float* agg_e = (float*)alloc((size_t)NE * 256 * 4);
    float* h_ent = (float*)alloc((size_t)NE * 256 * 4);
    float* h_psg = (float*)alloc((size_t)NP * 256 * 4);
    float* h_glob= (float*)alloc((size_t)NE * 256 * 4);
    float* relv  = (float*)alloc((size_t)NE * 4);
    float* ctxb  = (float*)alloc((size_t)NP * 256 * 4);
    float* qterm = (float*)alloc(256 * 4);
    unsigned short* warena  = (unsigned short*)alloc((size_t)12 * 65536 * 2);
    unsigned short* xe_bf   = (unsigned short*)alloc((size_t)NE * 256 * 2);
    unsigned short* xp_bf   = (unsigned short*)alloc((size_t)NP * 256 * 2);
    unsigned short* ge_bf   = (unsigned short*)alloc((size_t)NE * 256 * 2);
    unsigned short* gp_bf   = (unsigned short*)alloc((size_t)NP * 256 * 2);
    unsigned short* hent_bf = (unsigned short*)alloc((size_t)NE * 256 * 2);
    unsigned short* atto_bf = (unsigned short*)alloc((size_t)NE * 256 * 2);
    unsigned short* qkv_bf  = (unsigned short*)alloc((size_t)NE * 768 * 2);
    unsigned short* vt_bf   = (unsigned short*)alloc((size_t)256 * NE * 2);
    float* mpart = (float*)alloc((size_t)MSPLIT * NHEAD * NE * 4);
    float* lpart = (float*)alloc((size_t)MSPLIT * NHEAD * NE * 4);
    // opart (MSPLIT*NE*256 fp32 = 32 MB) aliases kqv_e..vt_e (33.5 MB contiguous):
    // all four buffers are dead once the hgt_attn dispatches complete,
    // before mha_mfma runs.
    float* opart = kqv_e;
    int* cnt_a = (int*)alloc((size_t)NP * 4);
    int* cur_a = (int*)alloc((size_t)NP * 4);
    int* ip_a  = (int*)alloc((size_t)(NP + 1) * 4);
    int* ss_a  = (int*)alloc((size_t)E * 4);
    int* cnt_b = (int*)alloc((size_t)NE * 4);
    int* cur_b = (int*)alloc((size_t)NE * 4);
    int* ip_b  = (int*)alloc((size_t)(NE + 1) * 4);
    int* ss_b  = (int*)alloc((size_t)E * 4);

    hipMemsetAsync(cnt_a, 0, (size_t)NP * 4, stream);
    hipMemsetAsync(cnt_b, 0, (size_t)NE * 4, stream);
    hipMemsetAsync(d_out, 0, (size_t)out_size * 4, stream);

    // ---- bf16 conversions (weights + inputs) ----
    cvt_w_kernel<<<dim3(32, 12), 256, 0, stream>>>(
        Wk_e, Wq_e, Wv_e, Wo_e, Wk_p, Wq_p, Wv_p, Wo_p,
        Wmi, Wmi + 65536, Wmi + 131072, Wmo, warena);
    cvt_bf16_kernel<0><<<NE * 256 / 2048, 256, 0, stream>>>(x_ent, xe_bf, NE * 32);
    cvt_bf16_kernel<0><<<NP * 256 / 2048, 256, 0, stream>>>(x_psg, xp_bf, NP * 32);

    const int eb = (E + 255) / 256;
    edge_count_kernel<<<eb, 256, 0, stream>>>(e2p_dst, cnt_a, E);
    edge_count_kernel<<<eb, 256, 0, stream>>>(p2e_dst, cnt_b, E);
    scan_kernel<<<1, 1024, 0, stream>>>(cnt_a, ip_a, cur_a);
    scan_kernel<<<1, 1024, 0, stream>>>(cnt_b, ip_b, cur_b);
    edge_scatter_kernel<<<eb, 256, 0, stream>>>(e2p_src, e2p_dst, cur_a, ss_a, E);
    edge_scatter_kernel<<<eb, 256, 0, stream>>>(p2e_src, p2e_dst, cur_b, ss_b, E);

    // HGT k|q|v projections (bf16 MFMA)
    bgemm_kernel<0,1,0><<<dim3(12, NE / 64), 256, 0, stream>>>(
        xe_bf, warena, warena + 65536, warena + 131072, bk_e, bq_e, bv_e,
        kqv_e, 768, nullptr, 0, nullptr, nullptr);
    bgemm_kernel<0,1,0><<<dim3(12, NP / 64), 256, 0, stream>>>(
        xp_bf, warena + 4*65536, warena + 5*65536, warena + 6*65536, bk_p, bq_p, bv_p,
        kqv_p, 768, nullptr, 0, nullptr, nullptr);

    rel_transform_kernel<<<dim3(NE / 64, NHEAD), 256, 0, stream>>>(kqv_e + 0,   768, a_e2p, kt_e);
    rel_transform_kernel<<<dim3(NE / 64, NHEAD), 256, 0, stream>>>(kqv_e + 512, 768, m_e2p, vt_e);
    rel_transform_kernel<<<dim3(NP / 64, NHEAD), 256, 0, stream>>>(kqv_p + 0,   768, a_p2e, kt_p);
    rel_transform_kernel<<<dim3(NP / 64, NHEAD), 256, 0, stream>>>(kqv_p + 512, 768, m_p2e, vt_p);

    hgt_attn_kernel<<<NP / 4, 256, 0, stream>>>(kqv_p + 256, kt_e, vt_e, p_e2p, ip_a, ss_a, agg_p);
    hgt_attn_kernel<<<NE / 4, 256, 0, stream>>>(kqv_e + 256, kt_p, vt_p, p_p2e, ip_b, ss_b, agg_e);

    // HGT out: gelu+cvt, then bf16 MFMA GEMM with sigmoid-skip epilogue
    cvt_bf16_kernel<1><<<NE * 256 / 2048, 256, 0, stream>>>(agg_e, ge_bf, NE * 32);
    cvt_bf16_kernel<1><<<NP * 256 / 2048, 256, 0, stream>>>(agg_p, gp_bf, NP * 32);
    bgemm_kernel<1,1,1><<<dim3(4, NE / 64), 256, 0, stream>>>(
        ge_bf, warena + 3*65536, warena + 3*65536, warena + 3*65536, bo_e, bo_e, bo_e,
        h_ent, 256, hent_bf, 256, x_ent, sk_e);
    bgemm_kernel<1,1,0><<<dim3(4, NP / 64), 256, 0, stream>>>(
        gp_bf, warena + 7*65536, warena + 7*65536, warena + 7*65536, bo_p, bo_p, bo_p,
        h_psg, 256, nullptr, 0, x_psg, sk_p);

    // MHA: qkv projection (bf16-only out), V-transpose, split-K 32x32 MFMA flash,
    // combine (bf16 out), out projection
    bgemm_kernel<0,0,1><<<dim3(12, NE / 64), 256, 0, stream>>>(
        hent_bf, warena + 8*65536, warena + 9*65536, warena + 10*65536,
        bmi, bmi + 256, bmi + 512,
        nullptr, 0, qkv_bf, 768, nullptr, nullptr);
    vtrans_kernel<<<dim3(NE / 64, NHEAD), 256, 0, stream>>>(qkv_bf, vt_bf, NE);
    mha_mfma_kernel<<<NHEAD * (NE / 32) * MSPLIT / 4, 256, 0, stream>>>(
        qkv_bf, vt_bf, opart, mpart, lpart, NE);
    mha_combine_kernel<<<NE, 256, 0, stream>>>(opart, mpart, lpart, atto_bf, NE);
    bgemm_kernel<0,1,0><<<dim3(4, NE / 64), 256, 0, stream>>>(
        atto_bf, warena + 11*65536, warena + 11*65536, warena + 11*65536, bmo, bmo, bmo,
        h_glob, 256, nullptr, 0, nullptr, nullptr);

    mix_ln_rel_kernel<<<NE / 4, 256, 0, stream>>>(h_ent, h_glob, lng_e, lnb_e, q_emb, relv);

    ctx_gather_kernel<<<NP, 256, 0, stream>>>(h_ent, relv, ip_a, ss_a, ctxb);
    psg_ln_kernel<<<NP / 4, 256, 0, stream>>>(h_psg, ctxb, lng_p, lnb_p);

    // scoring head (kept fp32)
    qterm_kernel<<<1, 256, 0, stream>>>(w1, b1, q_emb, qterm);
    gemm_kernel<0,2><<<dim3(4, NP / 64), 256, 0, stream>>>(
        h_psg, 256, w1, w1, w1, 512, qterm, qterm, qterm,
        nullptr, 256, 256, scores, w2, b2);
}